// Round 1
// baseline (555.265 us; speedup 1.0000x reference)
//
#include <hip/hip_runtime.h>
#include <math.h>

#define R_ 25
#define N_ 256
#define C_ 64
#define E_ 128
#define H_ 8
#define NC_ 27

__device__ __forceinline__ float waveReduceSum(float v) {
  #pragma unroll
  for (int off = 32; off > 0; off >>= 1) v += __shfl_xor(v, off);
  return v;
}

// -------------------- 1. emb layernorm (row-wise, E=128) --------------------
__global__ void k_emb_ln(const float* __restrict__ emb, const float* __restrict__ w,
                         const float* __restrict__ b, float* __restrict__ out) {
  int row = blockIdx.x;       // 6400
  int lane = threadIdx.x;     // 64
  const float* x = emb + (size_t)row * E_;
  float x0 = x[lane], x1 = x[lane + 64];
  float s = waveReduceSum(x0 + x1);
  float m = s * (1.0f / 128.0f);
  float d0 = x0 - m, d1 = x1 - m;
  float ss = waveReduceSum(d0 * d0 + d1 * d1);
  float inv = 1.0f / sqrtf(ss * (1.0f / 128.0f) + 1e-16f);
  float* o = out + (size_t)row * E_;
  o[lane]      = d0 * inv * w[lane]      + b[lane];
  o[lane + 64] = d1 * inv * w[lane + 64] + b[lane + 64];
}

// -------------------- 2. mean over trailing 4 --------------------
// dst[i] for i in [0,count): row = (i/256)*lstride + (i%256); mean of src[row*4..row*4+3]
__global__ void k_mean4(const float* __restrict__ src, float* __restrict__ dst,
                        int count, int lstride) {
  int i = blockIdx.x * 256 + threadIdx.x;
  if (i >= count) return;
  size_t row = (size_t)(i >> 8) * lstride + (i & 255);
  float4 v = *(const float4*)&src[row * 4];
  dst[i] = (v.x + v.y + v.z + v.w) * 0.25f;
}

// -------------------- 3. sqrt(softmax(mean4 over 27)) --------------------
__global__ void k_sqsm(const float* __restrict__ src, float* __restrict__ dst,
                       int count, int lstride) {
  int i = blockIdx.x * 256 + threadIdx.x;
  if (i >= count) return;
  size_t base = ((size_t)(i >> 8) * lstride + (i & 255)) * (NC_ * 4);
  float v[NC_];
  float mx = -1e30f;
  #pragma unroll
  for (int j = 0; j < NC_; ++j) {
    float4 t = *(const float4*)&src[base + j * 4];
    v[j] = (t.x + t.y + t.z + t.w) * 0.25f;
    mx = fmaxf(mx, v[j]);
  }
  float se = 0.0f;
  #pragma unroll
  for (int j = 0; j < NC_; ++j) se += expf(v[j] - mx);
  float lse = mx + logf(se);
  #pragma unroll
  for (int j = 0; j < NC_; ++j) dst[(size_t)i * NC_ + j] = expf(0.5f * (v[j] - lse));
}

// -------------------- 4. Q/K projection GEMM --------------------
// out[((r*8+h)*256+n)*128+f] = sum_e embln[r*256+n][e] * W[h][f][e]
__global__ __launch_bounds__(256, 1) void k_qk_gemm(const float* __restrict__ embln,
                                                    const float* __restrict__ W,
                                                    float* __restrict__ out) {
  int r = blockIdx.x, h = blockIdx.y;
  __shared__ float Wl[E_ * E_];      // e-quad swizzled by (f>>3)&3
  __shared__ float ews[64 * 129];
  const float* Wh = W + (size_t)h * E_ * E_;
  int t = threadIdx.x;
  for (int i = t * 4; i < E_ * E_; i += 1024) {
    float4 v = *(const float4*)&Wh[i];
    int f = i >> 7, e = i & 127;
    *(float4*)&Wl[(f << 7) + (e ^ (((f >> 3) & 3) << 2))] = v;
  }
  int n0 = (t & 15) << 2;
  int f0 = (t >> 4) << 3;
  int wswz = ((t >> 4) & 3) << 2;
  float* outp = out + ((size_t)(r * H_ + h)) * N_ * E_;

  for (int ch = 0; ch < 4; ++ch) {
    __syncthreads();
    for (int i = t; i < 64 * E_; i += 256) {
      int rr = i >> 7, e = i & 127;
      ews[rr * 129 + e] = embln[((size_t)(r * N_ + ch * 64 + rr)) * E_ + e];
    }
    __syncthreads();
    float acc[4][8];
    #pragma unroll
    for (int a = 0; a < 4; ++a)
      #pragma unroll
      for (int bb = 0; bb < 8; ++bb) acc[a][bb] = 0.0f;

    for (int e = 0; e < E_; e += 4) {
      float4 w4[8];
      #pragma unroll
      for (int ff = 0; ff < 8; ++ff)
        w4[ff] = *(const float4*)&Wl[((f0 + ff) << 7) + (e ^ wswz)];
      #pragma unroll
      for (int rr = 0; rr < 4; ++rr) {
        const float* er = &ews[(n0 + rr) * 129 + e];
        float a0 = er[0], a1 = er[1], a2 = er[2], a3 = er[3];
        #pragma unroll
        for (int ff = 0; ff < 8; ++ff)
          acc[rr][ff] += a0 * w4[ff].x + a1 * w4[ff].y + a2 * w4[ff].z + a3 * w4[ff].w;
      }
    }
    #pragma unroll
    for (int rr = 0; rr < 4; ++rr) {
      float4 o0 = make_float4(acc[rr][0], acc[rr][1], acc[rr][2], acc[rr][3]);
      float4 o1 = make_float4(acc[rr][4], acc[rr][5], acc[rr][6], acc[rr][7]);
      float* op = &outp[(size_t)(ch * 64 + n0 + rr) * E_ + f0];
      *(float4*)&op[0] = o0;
      *(float4*)&op[4] = o1;
    }
  }
}

// -------------------- 5. fused QK^T + softmax(axis n) + weighted reduce -----
// grid (L, H, 2). BR[(l*256+m)*8+h] = sum_n w[l,n]*softmax_n(S[n,m]).
__global__ __launch_bounds__(256, 2) void k_attn_br(
    const float* __restrict__ Q, const float* __restrict__ K,
    const int* __restrict__ idxv, int idx_stride,
    const float* __restrict__ wv, float* __restrict__ BR) {
  int l = blockIdx.x, h = blockIdx.y, z = blockIdx.z;
  int r = idxv[l * idx_stride];
  const float* Qp = Q + ((size_t)(r * H_ + h)) * N_ * E_;
  const float* Kp = K + ((size_t)(r * H_ + h)) * N_ * E_ + (size_t)z * 128 * E_;
  __shared__ float Ks[128 * E_];     // e-quad swizzled by (m>>2)&7
  __shared__ float red[8 * 128 * 3];
  int t = threadIdx.x;
  for (int i = t * 4; i < 128 * E_; i += 1024) {
    float4 v = *(const float4*)&Kp[i];
    int m = i >> 7, e = i & 127;
    *(float4*)&Ks[(m << 7) + (e ^ (((m >> 2) & 7) << 2))] = v;
  }
  __syncthreads();
  int s = t >> 5, l32 = t & 31;
  int c0 = l32 << 2;
  int kswz = (l32 & 7) << 2;
  const float* wrow = wv + (size_t)l * N_;
  float M[4], den[4], num[4];
  #pragma unroll
  for (int cc = 0; cc < 4; ++cc) { M[cc] = -1e30f; den[cc] = 0.0f; num[cc] = 0.0f; }
  const float scale = 0.08838834764831845f;  // 1/sqrt(128)

  for (int nb = 0; nb < 8; ++nb) {
    int n = s * 32 + nb * 4;
    const float* q0 = Qp + (size_t)n * E_;
    float acc[4][4];
    #pragma unroll
    for (int a = 0; a < 4; ++a)
      #pragma unroll
      for (int bb = 0; bb < 4; ++bb) acc[a][bb] = 0.0f;

    for (int e = 0; e < E_; e += 4) {
      float4 k4[4];
      #pragma unroll
      for (int cc = 0; cc < 4; ++cc)
        k4[cc] = *(const float4*)&Ks[((c0 + cc) << 7) + (e ^ kswz)];
      #pragma unroll
      for (int rr = 0; rr < 4; ++rr) {
        float4 q4 = *(const float4*)&q0[(size_t)rr * E_ + e];
        #pragma unroll
        for (int cc = 0; cc < 4; ++cc)
          acc[rr][cc] += q4.x * k4[cc].x + q4.y * k4[cc].y + q4.z * k4[cc].z + q4.w * k4[cc].w;
      }
    }
    float wgt0 = wrow[n], wgt1 = wrow[n + 1], wgt2 = wrow[n + 2], wgt3 = wrow[n + 3];
    #pragma unroll
    for (int cc = 0; cc < 4; ++cc) {
      float s0 = acc[0][cc] * scale, s1 = acc[1][cc] * scale;
      float s2 = acc[2][cc] * scale, s3 = acc[3][cc] * scale;
      float nm = fmaxf(fmaxf(fmaxf(s0, s1), fmaxf(s2, s3)), M[cc]);
      float f = __expf(M[cc] - nm);
      float e0 = __expf(s0 - nm), e1 = __expf(s1 - nm);
      float e2 = __expf(s2 - nm), e3 = __expf(s3 - nm);
      den[cc] = den[cc] * f + (e0 + e1 + e2 + e3);
      num[cc] = num[cc] * f + (wgt0 * e0 + wgt1 * e1 + wgt2 * e2 + wgt3 * e3);
      M[cc] = nm;
    }
  }
  #pragma unroll
  for (int cc = 0; cc < 4; ++cc) {
    float* rp = &red[((s << 7) + c0 + cc) * 3];
    rp[0] = M[cc]; rp[1] = den[cc]; rp[2] = num[cc];
  }
  __syncthreads();
  if (t < 128) {
    float gm = -1e30f;
    #pragma unroll
    for (int ss = 0; ss < 8; ++ss) gm = fmaxf(gm, red[((ss << 7) + t) * 3]);
    float d = 0.0f, nmm = 0.0f;
    #pragma unroll
    for (int ss = 0; ss < 8; ++ss) {
      const float* rp = &red[((ss << 7) + t) * 3];
      float f = __expf(rp[0] - gm);
      d += rp[1] * f;
      nmm += rp[2] * f;
    }
    BR[((size_t)l * N_ + z * 128 + t) * H_ + h] = nmm / d;
  }
}

// -------------------- 6. BS cosine similarity over H=8 --------------------
__global__ void k_bs(const float* __restrict__ BRt, const float* __restrict__ BRi,
                     float* __restrict__ out) {
  int i = blockIdx.x * 256 + threadIdx.x;   // < 409600
  int n = i & 255, c = (i >> 8) & 63, l = i >> 14;
  const float4* a = (const float4*)&BRt[((size_t)l * N_ + n) * H_];
  const float4* b = (const float4*)&BRi[((size_t)c * N_ + n) * H_];
  float4 a0 = a[0], a1 = a[1], b0 = b[0], b1 = b[1];
  float dot = a0.x * b0.x + a0.y * b0.y + a0.z * b0.z + a0.w * b0.w
            + a1.x * b1.x + a1.y * b1.y + a1.z * b1.z + a1.w * b1.w;
  float na = a0.x * a0.x + a0.y * a0.y + a0.z * a0.z + a0.w * a0.w
           + a1.x * a1.x + a1.y * a1.y + a1.z * a1.z + a1.w * a1.w;
  float nb = b0.x * b0.x + b0.y * b0.y + b0.z * b0.z + b0.w * b0.w
           + b1.x * b1.x + b1.y * b1.y + b1.z * b1.z + b1.w * b1.w;
  out[i] = dot / fmaxf(sqrtf(na) * sqrtf(nb), 1e-15f);
}

// -------------------- 7. CS = log(dot(sqrtP, sqrtQ))/27 --------------------
__global__ void k_cs(const float* __restrict__ S, const float* __restrict__ T,
                     float* __restrict__ out) {
  int i = blockIdx.x * 256 + threadIdx.x;   // < 409600
  int n = i & 255, c = (i >> 8) & 63, l = i >> 14;
  const float* sp = &S[((size_t)l * N_ + n) * NC_];
  const float* tp = &T[((size_t)c * N_ + n) * NC_];
  float dot = 0.0f;
  #pragma unroll
  for (int j = 0; j < NC_; ++j) dot += sp[j] * tp[j];
  out[i] = logf(dot) * (1.0f / 27.0f);
}

// -------------------- 8. OS projection --------------------
__global__ void k_proj(const float* __restrict__ emb, const int* __restrict__ idxi,
                       const int* __restrict__ biz, const float* __restrict__ Wos,
                       const float* __restrict__ bos, float* __restrict__ proj) {
  int c = blockIdx.x;       // 64
  int f = threadIdx.x;      // 128
  __shared__ float er[E_];
  int row = idxi[c] * N_ + biz[c];
  er[f] = emb[(size_t)row * E_ + f];
  __syncthreads();
  float acc = bos[f];
  const float* wr = &Wos[(size_t)f * E_];
  for (int e = 0; e < E_; e += 4) {
    float4 w4 = *(const float4*)&wr[e];
    acc += er[e] * w4.x + er[e + 1] * w4.y + er[e + 2] * w4.z + er[e + 3] * w4.w;
  }
  proj[c * E_ + f] = acc;
}

__global__ void k_os(const float* __restrict__ emb, const float* __restrict__ proj,
                     float* __restrict__ out) {
  int c = blockIdx.x, l = blockIdx.y, n = threadIdx.x;   // grid (64,25) block 256
  __shared__ float pr[E_];
  if (n < E_) pr[n] = proj[c * E_ + n];
  __syncthreads();
  const float* er = &emb[((size_t)l * N_ + n) * E_];
  float acc = 0.0f;
  for (int e = 0; e < E_; e += 4) {
    float4 v = *(const float4*)&er[e];
    acc += v.x * pr[e] + v.y * pr[e + 1] + v.z * pr[e + 2] + v.w * pr[e + 3];
  }
  out[((size_t)l * C_ + c) * N_ + n] = acc;
}

// -------------------- 9. final layernorm over (C,N) per r --------------------
__global__ void k_ln_final(float* __restrict__ out,
    const float* __restrict__ w0, const float* __restrict__ b0,
    const float* __restrict__ w1, const float* __restrict__ b1,
    const float* __restrict__ w2, const float* __restrict__ b2) {
  int r = blockIdx.x, o = blockIdx.y;     // grid (25,3), block 256
  const float* w = (o == 0) ? w0 : ((o == 1) ? w1 : w2);
  const float* b = (o == 0) ? b0 : ((o == 1) ? b1 : b2);
  float* x = out + (size_t)o * 409600 + (size_t)r * 16384;
  int t = threadIdx.x;
  __shared__ float redm[4];
  float s = 0.0f;
  for (int i = t; i < 16384; i += 256) s += x[i];
  s = waveReduceSum(s);
  if ((t & 63) == 0) redm[t >> 6] = s;
  __syncthreads();
  float m = (redm[0] + redm[1] + redm[2] + redm[3]) * (1.0f / 16384.0f);
  __syncthreads();
  float ss = 0.0f;
  for (int i = t; i < 16384; i += 256) { float d = x[i] - m; ss += d * d; }
  ss = waveReduceSum(ss);
  if ((t & 63) == 0) redm[t >> 6] = ss;
  __syncthreads();
  float v = (redm[0] + redm[1] + redm[2] + redm[3]) * (1.0f / 16384.0f);
  float inv = 1.0f / sqrtf(v + 1e-5f);
  for (int i = t; i < 16384; i += 256) x[i] = (x[i] - m) * inv * w[i] + b[i];
}

// -------------------- host launcher --------------------
extern "C" void kernel_launch(void* const* d_in, const int* in_sizes, int n_in,
                              void* d_out, int out_size, void* d_ws, size_t ws_size,
                              hipStream_t stream) {
  const float* bus_t  = (const float*)d_in[0];
  const float* bus_i  = (const float*)d_in[1];
  const float* cus_t  = (const float*)d_in[2];
  const float* cus_i  = (const float*)d_in[3];
  const int*   idx_t  = (const int*)d_in[4];
  const int*   idx_i  = (const int*)d_in[5];
  const int*   cov    = (const int*)d_in[6];
  const float* emb    = (const float*)d_in[7];
  const float* ln_w   = (const float*)d_in[8];
  const float* ln_b   = (const float*)d_in[9];
  const float* WQ_trg = (const float*)d_in[10];
  const float* WK_trg = (const float*)d_in[11];
  const float* WQ_inf = (const float*)d_in[12];
  const float* WK_inf = (const float*)d_in[13];
  const float* W_os   = (const float*)d_in[14];
  const float* b_os   = (const float*)d_in[15];
  const float* bs_w   = (const float*)d_in[16];
  const float* bs_b   = (const float*)d_in[17];
  const float* cs_w   = (const float*)d_in[18];
  const float* cs_b   = (const float*)d_in[19];
  const float* os_w   = (const float*)d_in[20];
  const float* os_b   = (const float*)d_in[21];

  float* ws = (float*)d_ws;
  float* embln = ws;                      // 819200
  float* Qb    = embln + 819200;          // 6553600
  float* Kb    = Qb + 6553600;            // 6553600
  float* bst   = Kb + 6553600;            // 6400
  float* bsi   = bst + 6400;              // 16384
  float* Ssq   = bsi + 16384;             // 172800
  float* Tsq   = Ssq + 172800;            // 442368
  float* BRt   = Tsq + 442368;            // 51200
  float* BRi   = BRt + 51200;             // 131072
  float* projb = BRi + 131072;            // 8192

  float* outBS = (float*)d_out;
  float* outCS = outBS + 409600;
  float* outOS = outCS + 409600;

  k_emb_ln<<<6400, 64, 0, stream>>>(emb, ln_w, ln_b, embln);
  k_mean4<<<25, 256, 0, stream>>>(bus_t, bst, R_ * N_, C_ * N_);
  k_mean4<<<64, 256, 0, stream>>>(bus_i, bsi, C_ * N_, N_);
  k_sqsm<<<25, 256, 0, stream>>>(cus_t, Ssq, R_ * N_, C_ * N_);
  k_sqsm<<<64, 256, 0, stream>>>(cus_i, Tsq, C_ * N_, N_);

  dim3 gq(R_, H_);
  k_qk_gemm<<<gq, 256, 0, stream>>>(embln, WQ_trg, Qb);
  k_qk_gemm<<<gq, 256, 0, stream>>>(embln, WK_trg, Kb);
  dim3 gat(R_, H_, 2);
  k_attn_br<<<gat, 256, 0, stream>>>(Qb, Kb, idx_t, C_, bst, BRt);

  k_qk_gemm<<<gq, 256, 0, stream>>>(embln, WQ_inf, Qb);
  k_qk_gemm<<<gq, 256, 0, stream>>>(embln, WK_inf, Kb);
  dim3 gai(C_, H_, 2);
  k_attn_br<<<gai, 256, 0, stream>>>(Qb, Kb, idx_i, 1, bsi, BRi);

  k_bs<<<1600, 256, 0, stream>>>(BRt, BRi, outBS);
  k_cs<<<1600, 256, 0, stream>>>(Ssq, Tsq, outCS);
  k_proj<<<64, 128, 0, stream>>>(emb, idx_i, cov, W_os, b_os, projb);
  k_os<<<dim3(C_, R_), 256, 0, stream>>>(emb, projb, outOS);

  k_ln_final<<<dim3(R_, 3), 256, 0, stream>>>(outBS, bs_w, bs_b, cs_w, cs_b, os_w, os_b);
}

// Round 2
// 414.792 us; speedup vs baseline: 1.3387x; 1.3387x over previous
//
#include <hip/hip_runtime.h>
#include <math.h>

#define R_ 25
#define N_ 256
#define C_ 64
#define E_ 128
#define H_ 8
#define NC_ 27

typedef _Float16 half2v __attribute__((ext_vector_type(2)));
union H2U { uint u; half2v h; ushort s[2]; };

__device__ __forceinline__ float fdot2f(uint a, uint b, float c) {
  H2U ua, ub; ua.u = a; ub.u = b;
#if __has_builtin(__builtin_amdgcn_fdot2)
  return __builtin_amdgcn_fdot2(ua.h, ub.h, c, false);
#else
  return c + (float)ua.h[0] * (float)ub.h[0] + (float)ua.h[1] * (float)ub.h[1];
#endif
}

__device__ __forceinline__ float h16tof(ushort v) {
  union { ushort s; _Float16 h; } u; u.s = v; return (float)u.h;
}

__device__ __forceinline__ float waveReduceSum(float v) {
  #pragma unroll
  for (int off = 32; off > 0; off >>= 1) v += __shfl_xor(v, off);
  return v;
}

// pair-granularity LDS swizzle (p = u32-pair index 0..31)
#define PSWZ(row) (((row) >> 2) & 15)

// -------------------- 1. emb layernorm -> f16 --------------------
__global__ void k_emb_ln16(const float* __restrict__ emb, const float* __restrict__ w,
                           const float* __restrict__ b, ushort* __restrict__ out) {
  int row = blockIdx.x;       // 6400
  int lane = threadIdx.x;     // 64
  const float2* x = (const float2*)(emb + (size_t)row * E_);
  float2 v = x[lane];
  float s = waveReduceSum(v.x + v.y);
  float m = s * (1.0f / 128.0f);
  float d0 = v.x - m, d1 = v.y - m;
  float ss = waveReduceSum(d0 * d0 + d1 * d1);
  float inv = 1.0f / sqrtf(ss * (1.0f / 128.0f) + 1e-16f);
  float2 wv = ((const float2*)w)[lane];
  float2 bv = ((const float2*)b)[lane];
  H2U u;
  u.h[0] = (_Float16)(d0 * inv * wv.x + bv.x);
  u.h[1] = (_Float16)(d1 * inv * wv.y + bv.y);
  ((uint*)out)[(size_t)row * 64 + lane] = u.u;
}

// -------------------- 2. mean over trailing 4 --------------------
__global__ void k_mean4(const float* __restrict__ src, float* __restrict__ dst,
                        int count, int lstride) {
  int i = blockIdx.x * 256 + threadIdx.x;
  if (i >= count) return;
  size_t row = (size_t)(i >> 8) * lstride + (i & 255);
  float4 v = *(const float4*)&src[row * 4];
  dst[i] = (v.x + v.y + v.z + v.w) * 0.25f;
}

// -------------------- 3. sqrt(softmax(mean4 over 27)) --------------------
__global__ void k_sqsm(const float* __restrict__ src, float* __restrict__ dst,
                       int count, int lstride) {
  int i = blockIdx.x * 256 + threadIdx.x;
  if (i >= count) return;
  size_t base = ((size_t)(i >> 8) * lstride + (i & 255)) * (NC_ * 4);
  float v[NC_];
  float mx = -1e30f;
  #pragma unroll
  for (int j = 0; j < NC_; ++j) {
    float4 t = *(const float4*)&src[base + j * 4];
    v[j] = (t.x + t.y + t.z + t.w) * 0.25f;
    mx = fmaxf(mx, v[j]);
  }
  float se = 0.0f;
  #pragma unroll
  for (int j = 0; j < NC_; ++j) se += expf(v[j] - mx);
  float lse = mx + logf(se);
  #pragma unroll
  for (int j = 0; j < NC_; ++j) dst[(size_t)i * NC_ + j] = expf(0.5f * (v[j] - lse));
}

// -------------------- 4. Q/K projection GEMM (f16 in, f16 out, fdot2) ------
// out[(r*8+h)*256+n][f] = sum_e embf16[r*256+n][e] * W[h][f][e]
__global__ __launch_bounds__(256, 2) void k_proj_qk(
    const ushort* __restrict__ embf16, const float* __restrict__ W,
    ushort* __restrict__ out) {
  int r = blockIdx.x, h = blockIdx.y;
  __shared__ uint Wl[128 * 64];   // [f][e2 swizzled]
  __shared__ uint ews[64 * 64];   // [n][e2 swizzled]
  int t = threadIdx.x;
  const float* Wh = W + (size_t)h * E_ * E_;
  for (int i = t; i < 128 * 64; i += 256) {
    int f = i >> 6, e2 = i & 63;
    float2 w2 = *(const float2*)&Wh[(f << 7) + (e2 << 1)];
    H2U u; u.h[0] = (_Float16)w2.x; u.h[1] = (_Float16)w2.y;
    int p = e2 >> 1;
    Wl[(f << 6) + (((p ^ PSWZ(f)) << 1) | (e2 & 1))] = u.u;
  }
  int n0 = (t & 15) << 2;
  int f0 = (t >> 4) << 3;

  for (int ch = 0; ch < 4; ++ch) {
    __syncthreads();
    const uint* eln = (const uint*)(embf16 + (size_t)(r * N_ + ch * 64) * E_);
    for (int i = t; i < 64 * 64; i += 256) {
      int n = i >> 6, e2 = i & 63;
      int p = e2 >> 1;
      ews[(n << 6) + (((p ^ PSWZ(n)) << 1) | (e2 & 1))] = eln[i];
    }
    __syncthreads();
    float acc[4][8];
    #pragma unroll
    for (int a = 0; a < 4; ++a)
      #pragma unroll
      for (int bb = 0; bb < 8; ++bb) acc[a][bb] = 0.0f;

    for (int p = 0; p < 32; ++p) {   // 4 e per iter
      uint2 w4[8];
      #pragma unroll
      for (int ff = 0; ff < 8; ++ff) {
        int f = f0 + ff;
        w4[ff] = *(const uint2*)&Wl[(f << 6) + ((p ^ PSWZ(f)) << 1)];
      }
      #pragma unroll
      for (int rr = 0; rr < 4; ++rr) {
        int n = n0 + rr;
        uint2 q4 = *(const uint2*)&ews[(n << 6) + ((p ^ PSWZ(n)) << 1)];
        #pragma unroll
        for (int ff = 0; ff < 8; ++ff) {
          acc[rr][ff] = fdot2f(q4.x, w4[ff].x, acc[rr][ff]);
          acc[rr][ff] = fdot2f(q4.y, w4[ff].y, acc[rr][ff]);
        }
      }
    }
    ushort* op = out + ((size_t)(r * H_ + h) * N_ + ch * 64) * E_;
    #pragma unroll
    for (int rr = 0; rr < 4; ++rr) {
      H2U a, bq, c, d;
      a.h[0]  = (_Float16)acc[rr][0]; a.h[1]  = (_Float16)acc[rr][1];
      bq.h[0] = (_Float16)acc[rr][2]; bq.h[1] = (_Float16)acc[rr][3];
      c.h[0]  = (_Float16)acc[rr][4]; c.h[1]  = (_Float16)acc[rr][5];
      d.h[0]  = (_Float16)acc[rr][6]; d.h[1]  = (_Float16)acc[rr][7];
      uint4 o = make_uint4(a.u, bq.u, c.u, d.u);
      *(uint4*)&op[(size_t)(n0 + rr) * E_ + f0] = o;
    }
  }
}

// -------------------- 5. S = scaled QK^T (f16) + softmax stats over n ------
// grid (25, 8, 2). S16[((r*8+h)*256+n)*256+m], stats per (rh, m).
__global__ __launch_bounds__(256, 2) void k_qks(
    const ushort* __restrict__ Q16, const ushort* __restrict__ K16,
    ushort* __restrict__ S16, float* __restrict__ statsM, float* __restrict__ statsD) {
  int r = blockIdx.x, h = blockIdx.y, z = blockIdx.z;
  int rh = r * H_ + h;
  __shared__ uint Ks[128 * 64];        // [m][e2 swizzled]
  __shared__ float red[8 * 128 * 2];
  int t = threadIdx.x;
  const uint* Kp = (const uint*)(K16 + ((size_t)rh * N_ + z * 128) * E_);
  for (int i = t; i < 128 * 64; i += 256) {
    int m = i >> 6, e2 = i & 63;
    int p = e2 >> 1;
    Ks[(m << 6) + (((p ^ PSWZ(m)) << 1) | (e2 & 1))] = Kp[i];
  }
  __syncthreads();
  int s = t >> 5, l32 = t & 31;
  int c0 = l32 << 2;
  const ushort* Qp = Q16 + (size_t)rh * N_ * E_;
  float M[4], den[4];
  #pragma unroll
  for (int cc = 0; cc < 4; ++cc) { M[cc] = -1e30f; den[cc] = 0.0f; }
  const float scale = 0.08838834764831845f;  // 1/sqrt(128)

  for (int nb = 0; nb < 8; ++nb) {
    int n = s * 32 + nb * 4;
    const uint* q0 = (const uint*)(Qp + (size_t)n * E_);
    float acc[4][4];
    #pragma unroll
    for (int a = 0; a < 4; ++a)
      #pragma unroll
      for (int bb = 0; bb < 4; ++bb) acc[a][bb] = 0.0f;

    for (int p = 0; p < 32; ++p) {     // 4 e per iter
      uint2 k4[4];
      #pragma unroll
      for (int cc = 0; cc < 4; ++cc)
        k4[cc] = *(const uint2*)&Ks[((c0 + cc) << 6) + ((p ^ (l32 & 15)) << 1)];
      #pragma unroll
      for (int rr = 0; rr < 4; ++rr) {
        uint2 q4 = *(const uint2*)&q0[rr * 64 + (p << 1)];
        #pragma unroll
        for (int cc = 0; cc < 4; ++cc) {
          acc[rr][cc] = fdot2f(q4.x, k4[cc].x, acc[rr][cc]);
          acc[rr][cc] = fdot2f(q4.y, k4[cc].y, acc[rr][cc]);
        }
      }
    }
    // round to f16 (so den is consistent with stored S), store, update stats
    float sv[4][4];
    #pragma unroll
    for (int rr = 0; rr < 4; ++rr)
      #pragma unroll
      for (int cc = 0; cc < 4; ++cc) {
        _Float16 hf = (_Float16)(acc[rr][cc] * scale);
        sv[rr][cc] = (float)hf;
      }
    #pragma unroll
    for (int rr = 0; rr < 4; ++rr) {
      H2U p0, p1;
      p0.h[0] = (_Float16)sv[rr][0]; p0.h[1] = (_Float16)sv[rr][1];
      p1.h[0] = (_Float16)sv[rr][2]; p1.h[1] = (_Float16)sv[rr][3];
      size_t srow = ((size_t)(rh * N_ + n + rr)) << 8;
      *(uint2*)&S16[srow + z * 128 + c0] = make_uint2(p0.u, p1.u);
    }
    #pragma unroll
    for (int cc = 0; cc < 4; ++cc) {
      float s0 = sv[0][cc], s1 = sv[1][cc], s2 = sv[2][cc], s3 = sv[3][cc];
      float nm = fmaxf(fmaxf(fmaxf(s0, s1), fmaxf(s2, s3)), M[cc]);
      float f = __expf(M[cc] - nm);
      den[cc] = den[cc] * f + __expf(s0 - nm) + __expf(s1 - nm)
                            + __expf(s2 - nm) + __expf(s3 - nm);
      M[cc] = nm;
    }
  }
  #pragma unroll
  for (int cc = 0; cc < 4; ++cc) {
    float* rp = &red[((s << 7) + c0 + cc) * 2];
    rp[0] = M[cc]; rp[1] = den[cc];
  }
  __syncthreads();
  if (t < 128) {
    float gm = -1e30f;
    #pragma unroll
    for (int ss = 0; ss < 8; ++ss) gm = fmaxf(gm, red[((ss << 7) + t) * 2]);
    float d = 0.0f;
    #pragma unroll
    for (int ss = 0; ss < 8; ++ss) {
      const float* rp = &red[((ss << 7) + t) * 2];
      d += rp[1] * __expf(rp[0] - gm);
    }
    statsM[rh * N_ + z * 128 + t] = gm;
    statsD[rh * N_ + z * 128 + t] = d;
  }
}

// -------------------- 6. BR[l,m,h] = sum_n w[l,n]*exp(S-M)/den -------------
__global__ void k_br(const ushort* __restrict__ S16, const float* __restrict__ statsM,
                     const float* __restrict__ statsD, const int* __restrict__ idxv,
                     int idx_stride, const float* __restrict__ wv, float* __restrict__ BR) {
  int l = blockIdx.x, h = blockIdx.y;
  int r = idxv[l * idx_stride];
  int rh = r * H_ + h;
  __shared__ float wl[N_];
  int t = threadIdx.x;   // m
  wl[t] = wv[(size_t)l * N_ + t];
  __syncthreads();
  float Mv = statsM[rh * N_ + t], Dv = statsD[rh * N_ + t];
  const ushort* Sp = S16 + (((size_t)rh * N_) << 8) + t;
  float a0 = 0, a1 = 0, a2 = 0, a3 = 0;
  for (int n = 0; n < N_; n += 4) {
    a0 += wl[n]     * __expf(h16tof(Sp[(size_t)(n)     << 8]) - Mv);
    a1 += wl[n + 1] * __expf(h16tof(Sp[(size_t)(n + 1) << 8]) - Mv);
    a2 += wl[n + 2] * __expf(h16tof(Sp[(size_t)(n + 2) << 8]) - Mv);
    a3 += wl[n + 3] * __expf(h16tof(Sp[(size_t)(n + 3) << 8]) - Mv);
  }
  BR[((size_t)l * N_ + t) * H_ + h] = (a0 + a1 + a2 + a3) / Dv;
}

// -------------------- 7. BS cosine similarity over H=8 --------------------
__global__ void k_bs(const float* __restrict__ BRt, const float* __restrict__ BRi,
                     float* __restrict__ out) {
  int i = blockIdx.x * 256 + threadIdx.x;   // < 409600
  int n = i & 255, c = (i >> 8) & 63, l = i >> 14;
  const float4* a = (const float4*)&BRt[((size_t)l * N_ + n) * H_];
  const float4* b = (const float4*)&BRi[((size_t)c * N_ + n) * H_];
  float4 a0 = a[0], a1 = a[1], b0 = b[0], b1 = b[1];
  float dot = a0.x * b0.x + a0.y * b0.y + a0.z * b0.z + a0.w * b0.w
            + a1.x * b1.x + a1.y * b1.y + a1.z * b1.z + a1.w * b1.w;
  float na = a0.x * a0.x + a0.y * a0.y + a0.z * a0.z + a0.w * a0.w
           + a1.x * a1.x + a1.y * a1.y + a1.z * a1.z + a1.w * a1.w;
  float nb = b0.x * b0.x + b0.y * b0.y + b0.z * b0.z + b0.w * b0.w
           + b1.x * b1.x + b1.y * b1.y + b1.z * b1.z + b1.w * b1.w;
  out[i] = dot / fmaxf(sqrtf(na) * sqrtf(nb), 1e-15f);
}

// -------------------- 8. CS = log(dot(sqrtP, sqrtQ))/27 --------------------
__global__ void k_cs(const float* __restrict__ S, const float* __restrict__ T,
                     float* __restrict__ out) {
  int i = blockIdx.x * 256 + threadIdx.x;   // < 409600
  int n = i & 255, c = (i >> 8) & 63, l = i >> 14;
  const float* sp = &S[((size_t)l * N_ + n) * NC_];
  const float* tp = &T[((size_t)c * N_ + n) * NC_];
  float dot = 0.0f;
  #pragma unroll
  for (int j = 0; j < NC_; ++j) dot += sp[j] * tp[j];
  out[i] = logf(dot) * (1.0f / 27.0f);
}

// -------------------- 9. OS projection --------------------
__global__ void k_proj(const float* __restrict__ emb, const int* __restrict__ idxi,
                       const int* __restrict__ biz, const float* __restrict__ Wos,
                       const float* __restrict__ bos, float* __restrict__ proj) {
  int c = blockIdx.x;       // 64
  int f = threadIdx.x;      // 128
  __shared__ float er[E_];
  int row = idxi[c] * N_ + biz[c];
  er[f] = emb[(size_t)row * E_ + f];
  __syncthreads();
  float acc = bos[f];
  const float* wr = &Wos[(size_t)f * E_];
  for (int e = 0; e < E_; e += 4) {
    float4 w4 = *(const float4*)&wr[e];
    acc += er[e] * w4.x + er[e + 1] * w4.y + er[e + 2] * w4.z + er[e + 3] * w4.w;
  }
  proj[c * E_ + f] = acc;
}

__global__ void k_os(const float* __restrict__ emb, const float* __restrict__ proj,
                     float* __restrict__ out) {
  int c = blockIdx.x, l = blockIdx.y, n = threadIdx.x;   // grid (64,25) block 256
  __shared__ float pr[E_];
  if (n < E_) pr[n] = proj[c * E_ + n];
  __syncthreads();
  const float* er = &emb[((size_t)l * N_ + n) * E_];
  float acc = 0.0f;
  for (int e = 0; e < E_; e += 4) {
    float4 v = *(const float4*)&er[e];
    acc += v.x * pr[e] + v.y * pr[e + 1] + v.z * pr[e + 2] + v.w * pr[e + 3];
  }
  out[((size_t)l * C_ + c) * N_ + n] = acc;
}

// -------------------- 10. final layernorm over (C,N) per r --------------------
__global__ void k_ln_final(float* __restrict__ out,
    const float* __restrict__ w0, const float* __restrict__ b0,
    const float* __restrict__ w1, const float* __restrict__ b1,
    const float* __restrict__ w2, const float* __restrict__ b2) {
  int r = blockIdx.x, o = blockIdx.y;     // grid (25,3), block 256
  const float* w = (o == 0) ? w0 : ((o == 1) ? w1 : w2);
  const float* b = (o == 0) ? b0 : ((o == 1) ? b1 : b2);
  float* x = out + (size_t)o * 409600 + (size_t)r * 16384;
  int t = threadIdx.x;
  __shared__ float redm[4];
  float s = 0.0f;
  for (int i = t; i < 16384; i += 256) s += x[i];
  s = waveReduceSum(s);
  if ((t & 63) == 0) redm[t >> 6] = s;
  __syncthreads();
  float m = (redm[0] + redm[1] + redm[2] + redm[3]) * (1.0f / 16384.0f);
  __syncthreads();
  float ss = 0.0f;
  for (int i = t; i < 16384; i += 256) { float d = x[i] - m; ss += d * d; }
  ss = waveReduceSum(ss);
  if ((t & 63) == 0) redm[t >> 6] = ss;
  __syncthreads();
  float v = (redm[0] + redm[1] + redm[2] + redm[3]) * (1.0f / 16384.0f);
  float inv = 1.0f / sqrtf(v + 1e-5f);
  for (int i = t; i < 16384; i += 256) x[i] = (x[i] - m) * inv * w[i] + b[i];
}

// -------------------- host launcher --------------------
extern "C" void kernel_launch(void* const* d_in, const int* in_sizes, int n_in,
                              void* d_out, int out_size, void* d_ws, size_t ws_size,
                              hipStream_t stream) {
  const float* bus_t  = (const float*)d_in[0];
  const float* bus_i  = (const float*)d_in[1];
  const float* cus_t  = (const float*)d_in[2];
  const float* cus_i  = (const float*)d_in[3];
  const int*   idx_t  = (const int*)d_in[4];
  const int*   idx_i  = (const int*)d_in[5];
  const int*   cov    = (const int*)d_in[6];
  const float* emb    = (const float*)d_in[7];
  const float* ln_w   = (const float*)d_in[8];
  const float* ln_b   = (const float*)d_in[9];
  const float* WQ_trg = (const float*)d_in[10];
  const float* WK_trg = (const float*)d_in[11];
  const float* WQ_inf = (const float*)d_in[12];
  const float* WK_inf = (const float*)d_in[13];
  const float* W_os   = (const float*)d_in[14];
  const float* b_os   = (const float*)d_in[15];
  const float* bs_w   = (const float*)d_in[16];
  const float* bs_b   = (const float*)d_in[17];
  const float* cs_w   = (const float*)d_in[18];
  const float* cs_b   = (const float*)d_in[19];
  const float* os_w   = (const float*)d_in[20];
  const float* os_b   = (const float*)d_in[21];

  float* ws = (float*)d_ws;
  // sizes in f32 slots
  ushort* emb16  = (ushort*)ws;                       // 819200 f16 = 409600 slots
  float*  base1  = ws + 409600;
  ushort* Q16    = (ushort*)base1;                    // 6553600 f16 = 3276800 slots
  ushort* K16    = (ushort*)(base1 + 3276800);        // 3276800 slots
  ushort* S16    = (ushort*)(base1 + 6553600);        // 13107200 f16 = 6553600 slots
  float*  statsM = base1 + 13107200;                  // 51200
  float*  statsD = statsM + 51200;                    // 51200
  float*  bst    = statsD + 51200;                    // 6400
  float*  bsi    = bst + 6400;                        // 16384
  float*  Ssq    = bsi + 16384;                       // 172800
  float*  Tsq    = Ssq + 172800;                      // 442368
  float*  BRt    = Tsq + 442368;                      // 51200
  float*  BRi    = BRt + 51200;                       // 131072
  float*  projb  = BRi + 131072;                      // 8192

  float* outBS = (float*)d_out;
  float* outCS = outBS + 409600;
  float* outOS = outCS + 409600;

  k_emb_ln16<<<6400, 64, 0, stream>>>(emb, ln_w, ln_b, emb16);
  k_mean4<<<25, 256, 0, stream>>>(bus_t, bst, R_ * N_, C_ * N_);
  k_mean4<<<64, 256, 0, stream>>>(bus_i, bsi, C_ * N_, N_);
  k_sqsm<<<25, 256, 0, stream>>>(cus_t, Ssq, R_ * N_, C_ * N_);
  k_sqsm<<<64, 256, 0, stream>>>(cus_i, Tsq, C_ * N_, N_);

  dim3 gq(R_, H_);
  dim3 gs(R_, H_, 2);
  // target set
  k_proj_qk<<<gq, 256, 0, stream>>>(emb16, WQ_trg, Q16);
  k_proj_qk<<<gq, 256, 0, stream>>>(emb16, WK_trg, K16);
  k_qks<<<gs, 256, 0, stream>>>(Q16, K16, S16, statsM, statsD);
  k_br<<<dim3(R_, H_), 256, 0, stream>>>(S16, statsM, statsD, idx_t, C_, bst, BRt);
  // infected set
  k_proj_qk<<<gq, 256, 0, stream>>>(emb16, WQ_inf, Q16);
  k_proj_qk<<<gq, 256, 0, stream>>>(emb16, WK_inf, K16);
  k_qks<<<gs, 256, 0, stream>>>(Q16, K16, S16, statsM, statsD);
  k_br<<<dim3(C_, H_), 256, 0, stream>>>(S16, statsM, statsD, idx_i, 1, bsi, BRi);

  k_bs<<<1600, 256, 0, stream>>>(BRt, BRi, outBS);
  k_cs<<<1600, 256, 0, stream>>>(Ssq, Tsq, outCS);
  k_proj<<<64, 128, 0, stream>>>(emb, idx_i, cov, W_os, b_os, projb);
  k_os<<<dim3(C_, R_), 256, 0, stream>>>(emb, projb, outOS);

  k_ln_final<<<dim3(R_, 3), 256, 0, stream>>>(outBS, bs_w, bs_b, cs_w, cs_b, os_w, os_b);
}

// Round 3
// 164.066 us; speedup vs baseline: 3.3844x; 2.5282x over previous
//
#include <hip/hip_runtime.h>
#include <math.h>

#define R_ 25
#define N_ 256
#define C_ 64
#define E_ 128
#define H_ 8
#define NC_ 27

typedef _Float16 f16x8 __attribute__((ext_vector_type(8)));
typedef float f32x16 __attribute__((ext_vector_type(16)));

union HU { ushort s; _Float16 h; };
__device__ __forceinline__ ushort ftoh(float f) { HU u; u.h = (_Float16)f; return u.s; }
__device__ __forceinline__ float htof(ushort s) { HU u; u.s = s; return (float)u.h; }

__device__ __forceinline__ float waveReduceSum(float v) {
  #pragma unroll
  for (int off = 32; off > 0; off >>= 1) v += __shfl_xor(v, off);
  return v;
}

// -------------------- 1. emb layernorm -> f16 (4 rows/block) --------------------
__global__ void k_emb_ln16(const float* __restrict__ emb, const float* __restrict__ w,
                           const float* __restrict__ b, ushort* __restrict__ out) {
  int row = blockIdx.x * 4 + (threadIdx.x >> 6);   // 6400 rows
  int lane = threadIdx.x & 63;
  const float2* x = (const float2*)(emb + (size_t)row * E_);
  float2 v = x[lane];
  float s = waveReduceSum(v.x + v.y);
  float m = s * (1.0f / 128.0f);
  float d0 = v.x - m, d1 = v.y - m;
  float ss = waveReduceSum(d0 * d0 + d1 * d1);
  float inv = 1.0f / sqrtf(ss * (1.0f / 128.0f) + 1e-16f);
  float2 wv = ((const float2*)w)[lane];
  float2 bv = ((const float2*)b)[lane];
  uint u = (uint)ftoh(d0 * inv * wv.x + bv.x) | ((uint)ftoh(d1 * inv * wv.y + bv.y) << 16);
  ((uint*)out)[(size_t)row * 64 + lane] = u;
}

// -------------------- 2. mean over trailing 4 (both sets) --------------------
__global__ void k_mean4_all(const float* __restrict__ bus_t, const float* __restrict__ bus_i,
                            float* __restrict__ bst, float* __restrict__ bsi) {
  int i = blockIdx.x * 256 + threadIdx.x;
  if (i < R_ * N_) {
    size_t row = (size_t)(i >> 8) * (C_ * N_) + (i & 255);
    float4 v = *(const float4*)&bus_t[row * 4];
    bst[i] = (v.x + v.y + v.z + v.w) * 0.25f;
  }
  int j = i - R_ * N_;
  if (j >= 0 && j < C_ * N_) {
    float4 v = *(const float4*)&bus_i[(size_t)j * 4];
    bsi[j] = (v.x + v.y + v.z + v.w) * 0.25f;
  }
}

// -------------------- 3. sqrt(softmax(mean4 over 27)) (both sets) ----------
__global__ void k_sqsm_all(const float* __restrict__ cus_t, const float* __restrict__ cus_i,
                           float* __restrict__ Ssq, float* __restrict__ Tsq) {
  int i = blockIdx.x * 256 + threadIdx.x;
  const float* src; float* dst; size_t base; int oi;
  if (i < R_ * N_) {
    src = cus_t; dst = Ssq; oi = i;
    base = ((size_t)(i >> 8) * (C_ * N_) + (i & 255)) * (NC_ * 4);
  } else {
    int j = i - R_ * N_;
    if (j >= C_ * N_) return;
    src = cus_i; dst = Tsq; oi = j;
    base = ((size_t)(j >> 8) * N_ + (j & 255)) * (NC_ * 4);
  }
  float v[NC_];
  float mx = -1e30f;
  #pragma unroll
  for (int j = 0; j < NC_; ++j) {
    float4 t = *(const float4*)&src[base + j * 4];
    v[j] = (t.x + t.y + t.z + t.w) * 0.25f;
    mx = fmaxf(mx, v[j]);
  }
  float se = 0.0f;
  #pragma unroll
  for (int j = 0; j < NC_; ++j) se += expf(v[j] - mx);
  float lse = mx + logf(se);
  #pragma unroll
  for (int j = 0; j < NC_; ++j) dst[(size_t)oi * NC_ + j] = expf(0.5f * (v[j] - lse));
}

// -------------------- 4. all 4 projections, MFMA --------------------
// out[(r*8+h)*256+n][f] = sum_e embf16[r*256+n][e] * W[h][f][e]
__global__ __launch_bounds__(512) void k_proj_mfma(
    const ushort* __restrict__ emb16,
    const float* __restrict__ W0, const float* __restrict__ W1,
    const float* __restrict__ W2, const float* __restrict__ W3,
    ushort* __restrict__ O0, ushort* __restrict__ O1,
    ushort* __restrict__ O2, ushort* __restrict__ O3) {
  int r = blockIdx.x, h = blockIdx.y, z = blockIdx.z;
  const float* W = (z == 0) ? W0 : (z == 1) ? W1 : (z == 2) ? W2 : W3;
  ushort* O = (z == 0) ? O0 : (z == 1) ? O1 : (z == 2) ? O2 : O3;
  const float* Wh = W + ((size_t)h << 14);
  __shared__ ushort Bl[128 * 128];
  int t = threadIdx.x;
  for (int c = t; c < 2048; c += 512) {
    int f = c >> 4, s = c & 15;
    const float4* src = (const float4*)(Wh + (f << 7) + (s << 3));
    float4 x = src[0], y = src[1];
    uint4 pk;
    pk.x = (uint)ftoh(x.x) | ((uint)ftoh(x.y) << 16);
    pk.y = (uint)ftoh(x.z) | ((uint)ftoh(x.w) << 16);
    pk.z = (uint)ftoh(y.x) | ((uint)ftoh(y.y) << 16);
    pk.w = (uint)ftoh(y.z) | ((uint)ftoh(y.w) << 16);
    *(uint4*)&Bl[(f << 7) + ((s << 3) ^ ((f & 15) << 3))] = pk;
  }
  __syncthreads();
  int w = t >> 6, l = t & 63, lo = l & 31, hi = l >> 5;
  f32x16 acc[4];
  #pragma unroll
  for (int i = 0; i < 4; ++i)
    #pragma unroll
    for (int j = 0; j < 16; ++j) acc[i][j] = 0.0f;

  const ushort* Ap = emb16 + (((size_t)(r * N_) + (w << 5) + lo) << 7) + (hi << 3);
  #pragma unroll
  for (int ks = 0; ks < 8; ++ks) {
    f16x8 a = *(const f16x8*)(Ap + (ks << 4));
    #pragma unroll
    for (int tl = 0; tl < 4; ++tl) {
      int f = (tl << 5) + lo;
      f16x8 b = *(const f16x8*)&Bl[(f << 7) + ((((ks << 4) + (hi << 3))) ^ ((f & 15) << 3))];
      acc[tl] = __builtin_amdgcn_mfma_f32_32x32x16_f16(a, b, acc[tl], 0, 0, 0);
    }
  }
  ushort* Op = O + (((size_t)(r * H_ + h) * N_) << 7);
  #pragma unroll
  for (int tl = 0; tl < 4; ++tl)
    #pragma unroll
    for (int rg = 0; rg < 16; ++rg) {
      int row = (rg & 3) + ((rg >> 2) << 3) + (hi << 2);
      int n = (w << 5) + row;
      Op[((size_t)n << 7) + (tl << 5) + lo] = ftoh(acc[tl][rg]);
    }
}

// -------------------- 5. QK^T (MFMA) + f16 S + softmax stats over n --------
// grid (25, 8, 4): z = set*2 + mhalf. S[rh][n][m], stats per (rh, m).
__global__ __launch_bounds__(512) void k_qks_mfma(
    const ushort* __restrict__ Qt, const ushort* __restrict__ Kt,
    const ushort* __restrict__ Qi, const ushort* __restrict__ Ki,
    ushort* __restrict__ St, ushort* __restrict__ Si,
    float* __restrict__ sMt, float* __restrict__ sDt,
    float* __restrict__ sMi, float* __restrict__ sDi) {
  int r = blockIdx.x, h = blockIdx.y, z = blockIdx.z;
  int set = z >> 1, zm = z & 1;
  const ushort* Q = set ? Qi : Qt;
  const ushort* K = set ? Ki : Kt;
  ushort* S = set ? Si : St;
  float* sM = set ? sMi : sMt;
  float* sD = set ? sDi : sDt;
  int rh = r * H_ + h;
  __shared__ ushort Bl[128 * 128];
  __shared__ float redM[8 * 128];
  __shared__ float redD[8 * 128];
  __shared__ float gmax[128];
  int t = threadIdx.x;
  const ushort* Kp = K + (((size_t)rh * N_ + zm * 128) << 7);
  for (int c = t; c < 2048; c += 512) {
    int m = c >> 4, s = c & 15;
    uint4 v = *(const uint4*)(Kp + (m << 7) + (s << 3));
    *(uint4*)&Bl[(m << 7) + ((s << 3) ^ ((m & 15) << 3))] = v;
  }
  __syncthreads();
  int w = t >> 6, l = t & 63, lo = l & 31, hi = l >> 5;
  f32x16 acc[4];
  #pragma unroll
  for (int i = 0; i < 4; ++i)
    #pragma unroll
    for (int j = 0; j < 16; ++j) acc[i][j] = 0.0f;

  const ushort* Ap = Q + (((size_t)rh * N_ + (w << 5) + lo) << 7) + (hi << 3);
  #pragma unroll
  for (int ks = 0; ks < 8; ++ks) {
    f16x8 a = *(const f16x8*)(Ap + (ks << 4));
    #pragma unroll
    for (int tl = 0; tl < 4; ++tl) {
      int m = (tl << 5) + lo;
      f16x8 b = *(const f16x8*)&Bl[(m << 7) + ((((ks << 4) + (hi << 3))) ^ ((m & 15) << 3))];
      acc[tl] = __builtin_amdgcn_mfma_f32_32x32x16_f16(a, b, acc[tl], 0, 0, 0);
    }
  }
  // scale + round to f16 (stats consistent with stored S)
  const float scale = 0.08838834764831845f;
  #pragma unroll
  for (int tl = 0; tl < 4; ++tl)
    #pragma unroll
    for (int rg = 0; rg < 16; ++rg)
      acc[tl][rg] = htof(ftoh(acc[tl][rg] * scale));
  // store S16
  ushort* Sp = S + (((size_t)rh * N_) << 8) + zm * 128;
  #pragma unroll
  for (int tl = 0; tl < 4; ++tl)
    #pragma unroll
    for (int rg = 0; rg < 16; ++rg) {
      int row = (rg & 3) + ((rg >> 2) << 3) + (hi << 2);
      int n = (w << 5) + row;
      Sp[((size_t)n << 8) + (tl << 5) + lo] = ftoh(acc[tl][rg]);
    }
  // per-wave per-col max
  #pragma unroll
  for (int tl = 0; tl < 4; ++tl) {
    float mx = acc[tl][0];
    #pragma unroll
    for (int rg = 1; rg < 16; ++rg) mx = fmaxf(mx, acc[tl][rg]);
    mx = fmaxf(mx, __shfl_xor(mx, 32));
    if (hi == 0) redM[(w << 7) + (tl << 5) + lo] = mx;
  }
  __syncthreads();
  if (t < 128) {
    float g = redM[t];
    #pragma unroll
    for (int ww = 1; ww < 8; ++ww) g = fmaxf(g, redM[(ww << 7) + t]);
    gmax[t] = g;
  }
  __syncthreads();
  // per-wave per-col sum of exp
  #pragma unroll
  for (int tl = 0; tl < 4; ++tl) {
    float g = gmax[(tl << 5) + lo];
    float s = 0.0f;
    #pragma unroll
    for (int rg = 0; rg < 16; ++rg) s += __expf(acc[tl][rg] - g);
    s += __shfl_xor(s, 32);
    if (hi == 0) redD[(w << 7) + (tl << 5) + lo] = s;
  }
  __syncthreads();
  if (t < 128) {
    float d = 0.0f;
    #pragma unroll
    for (int ww = 0; ww < 8; ++ww) d += redD[(ww << 7) + t];
    sM[rh * N_ + zm * 128 + t] = gmax[t];
    sD[rh * N_ + zm * 128 + t] = d;
  }
}

// -------------------- 6. BR (both sets) --------------------
__global__ void k_br(const ushort* __restrict__ St, const ushort* __restrict__ Si,
                     const float* __restrict__ sMt, const float* __restrict__ sDt,
                     const float* __restrict__ sMi, const float* __restrict__ sDi,
                     const int* __restrict__ idx_t, const int* __restrict__ idx_i,
                     const float* __restrict__ bst, const float* __restrict__ bsi,
                     float* __restrict__ BRt, float* __restrict__ BRi) {
  int lb = blockIdx.x, h = blockIdx.y;
  int t = threadIdx.x;   // m
  const ushort* S; const float* sMv; const float* sDv; const float* wv; float* BR; int r;
  if (lb < R_) {
    int l = lb; r = idx_t[l * C_];
    S = St; sMv = sMt; sDv = sDt; wv = bst + (size_t)l * N_; BR = BRt + (size_t)l * N_ * H_;
  } else {
    int l = lb - R_; r = idx_i[l];
    S = Si; sMv = sMi; sDv = sDi; wv = bsi + (size_t)l * N_; BR = BRi + (size_t)l * N_ * H_;
  }
  int rh = r * H_ + h;
  __shared__ float wl[N_];
  wl[t] = wv[t];
  __syncthreads();
  float Mv = sMv[rh * N_ + t], Dv = sDv[rh * N_ + t];
  const ushort* Sp = S + (((size_t)rh * N_) << 8) + t;
  float a0 = 0, a1 = 0, a2 = 0, a3 = 0;
  for (int n = 0; n < N_; n += 4) {
    a0 += wl[n]     * __expf(htof(Sp[(size_t)(n)     << 8]) - Mv);
    a1 += wl[n + 1] * __expf(htof(Sp[(size_t)(n + 1) << 8]) - Mv);
    a2 += wl[n + 2] * __expf(htof(Sp[(size_t)(n + 2) << 8]) - Mv);
    a3 += wl[n + 3] * __expf(htof(Sp[(size_t)(n + 3) << 8]) - Mv);
  }
  BR[(size_t)t * H_ + h] = (a0 + a1 + a2 + a3) / Dv;
}

// -------------------- 7. BS + CS fused --------------------
__global__ void k_bscs(const float* __restrict__ BRt, const float* __restrict__ BRi,
                       const float* __restrict__ Ssq, const float* __restrict__ Tsq,
                       float* __restrict__ outBS, float* __restrict__ outCS) {
  int i = blockIdx.x * 256 + threadIdx.x;   // < 409600
  int n = i & 255, c = (i >> 8) & 63, l = i >> 14;
  const float4* a = (const float4*)&BRt[((size_t)l * N_ + n) * H_];
  const float4* b = (const float4*)&BRi[((size_t)c * N_ + n) * H_];
  float4 a0 = a[0], a1 = a[1], b0 = b[0], b1 = b[1];
  float dot = a0.x * b0.x + a0.y * b0.y + a0.z * b0.z + a0.w * b0.w
            + a1.x * b1.x + a1.y * b1.y + a1.z * b1.z + a1.w * b1.w;
  float na = a0.x * a0.x + a0.y * a0.y + a0.z * a0.z + a0.w * a0.w
           + a1.x * a1.x + a1.y * a1.y + a1.z * a1.z + a1.w * a1.w;
  float nb = b0.x * b0.x + b0.y * b0.y + b0.z * b0.z + b0.w * b0.w
           + b1.x * b1.x + b1.y * b1.y + b1.z * b1.z + b1.w * b1.w;
  outBS[i] = dot / fmaxf(sqrtf(na) * sqrtf(nb), 1e-15f);

  const float* sp = &Ssq[((size_t)l * N_ + n) * NC_];
  const float* tp = &Tsq[((size_t)c * N_ + n) * NC_];
  float d2 = 0.0f;
  #pragma unroll
  for (int j = 0; j < NC_; ++j) d2 += sp[j] * tp[j];
  outCS[i] = logf(d2) * (1.0f / 27.0f);
}

// -------------------- 8. OS projection --------------------
__global__ void k_proj_os(const float* __restrict__ emb, const int* __restrict__ idxi,
                          const int* __restrict__ biz, const float* __restrict__ Wos,
                          const float* __restrict__ bos, float* __restrict__ proj) {
  int c = blockIdx.x;       // 64
  int f = threadIdx.x;      // 128
  __shared__ float er[E_];
  int row = idxi[c] * N_ + biz[c];
  er[f] = emb[(size_t)row * E_ + f];
  __syncthreads();
  float acc = bos[f];
  const float* wr = &Wos[(size_t)f * E_];
  for (int e = 0; e < E_; e += 4) {
    float4 w4 = *(const float4*)&wr[e];
    acc += er[e] * w4.x + er[e + 1] * w4.y + er[e + 2] * w4.z + er[e + 3] * w4.w;
  }
  proj[c * E_ + f] = acc;
}

__global__ void k_os(const float* __restrict__ emb, const float* __restrict__ proj,
                     float* __restrict__ out) {
  int c = blockIdx.x, l = blockIdx.y, n = threadIdx.x;   // grid (64,25) block 256
  __shared__ float pr[E_];
  if (n < E_) pr[n] = proj[c * E_ + n];
  __syncthreads();
  const float* er = &emb[((size_t)l * N_ + n) * E_];
  float acc = 0.0f;
  for (int e = 0; e < E_; e += 4) {
    float4 v = *(const float4*)&er[e];
    acc += v.x * pr[e] + v.y * pr[e + 1] + v.z * pr[e + 2] + v.w * pr[e + 3];
  }
  out[((size_t)l * C_ + c) * N_ + n] = acc;
}

// -------------------- 9. final layernorm over (C,N) per r --------------------
__global__ void k_ln_final(float* __restrict__ out,
    const float* __restrict__ w0, const float* __restrict__ b0,
    const float* __restrict__ w1, const float* __restrict__ b1,
    const float* __restrict__ w2, const float* __restrict__ b2) {
  int r = blockIdx.x, o = blockIdx.y;     // grid (25,3), block 256
  const float* w = (o == 0) ? w0 : ((o == 1) ? w1 : w2);
  const float* b = (o == 0) ? b0 : ((o == 1) ? b1 : b2);
  float* x = out + (size_t)o * 409600 + (size_t)r * 16384;
  int t = threadIdx.x;
  __shared__ float redm[4];
  float s = 0.0f;
  for (int i = t; i < 16384; i += 256) s += x[i];
  s = waveReduceSum(s);
  if ((t & 63) == 0) redm[t >> 6] = s;
  __syncthreads();
  float m = (redm[0] + redm[1] + redm[2] + redm[3]) * (1.0f / 16384.0f);
  __syncthreads();
  float ss = 0.0f;
  for (int i = t; i < 16384; i += 256) { float d = x[i] - m; ss += d * d; }
  ss = waveReduceSum(ss);
  if ((t & 63) == 0) redm[t >> 6] = ss;
  __syncthreads();
  float v = (redm[0] + redm[1] + redm[2] + redm[3]) * (1.0f / 16384.0f);
  float inv = 1.0f / sqrtf(v + 1e-5f);
  for (int i = t; i < 16384; i += 256) x[i] = (x[i] - m) * inv * w[i] + b[i];
}

// -------------------- host launcher --------------------
extern "C" void kernel_launch(void* const* d_in, const int* in_sizes, int n_in,
                              void* d_out, int out_size, void* d_ws, size_t ws_size,
                              hipStream_t stream) {
  const float* bus_t  = (const float*)d_in[0];
  const float* bus_i  = (const float*)d_in[1];
  const float* cus_t  = (const float*)d_in[2];
  const float* cus_i  = (const float*)d_in[3];
  const int*   idx_t  = (const int*)d_in[4];
  const int*   idx_i  = (const int*)d_in[5];
  const int*   cov    = (const int*)d_in[6];
  const float* emb    = (const float*)d_in[7];
  const float* ln_w   = (const float*)d_in[8];
  const float* ln_b   = (const float*)d_in[9];
  const float* WQ_trg = (const float*)d_in[10];
  const float* WK_trg = (const float*)d_in[11];
  const float* WQ_inf = (const float*)d_in[12];
  const float* WK_inf = (const float*)d_in[13];
  const float* W_os   = (const float*)d_in[14];
  const float* b_os   = (const float*)d_in[15];
  const float* bs_w   = (const float*)d_in[16];
  const float* bs_b   = (const float*)d_in[17];
  const float* cs_w   = (const float*)d_in[18];
  const float* cs_b   = (const float*)d_in[19];
  const float* os_w   = (const float*)d_in[20];
  const float* os_b   = (const float*)d_in[21];

  float* ws = (float*)d_ws;
  // f32-slot layout
  ushort* emb16 = (ushort*)ws;                        // 409600 slots
  float*  p     = ws + 409600;
  ushort* Qt = (ushort*)p;          p += 3276800;
  ushort* Kt = (ushort*)p;          p += 3276800;
  ushort* Qi = (ushort*)p;          p += 3276800;
  ushort* Ki = (ushort*)p;          p += 3276800;
  ushort* St = (ushort*)p;          p += 6553600;
  ushort* Si = (ushort*)p;          p += 6553600;
  float* sMt = p;                   p += 51200;
  float* sDt = p;                   p += 51200;
  float* sMi = p;                   p += 51200;
  float* sDi = p;                   p += 51200;
  float* bst = p;                   p += 6400;
  float* bsi = p;                   p += 16384;
  float* Ssq = p;                   p += 172800;
  float* Tsq = p;                   p += 442368;
  float* BRt = p;                   p += 51200;
  float* BRi = p;                   p += 131072;
  float* projb = p;                 p += 8192;

  float* outBS = (float*)d_out;
  float* outCS = outBS + 409600;
  float* outOS = outCS + 409600;

  k_emb_ln16<<<1600, 256, 0, stream>>>(emb, ln_w, ln_b, emb16);
  k_mean4_all<<<89, 256, 0, stream>>>(bus_t, bus_i, bst, bsi);
  k_sqsm_all<<<89, 256, 0, stream>>>(cus_t, cus_i, Ssq, Tsq);

  k_proj_mfma<<<dim3(R_, H_, 4), 512, 0, stream>>>(emb16, WQ_trg, WK_trg, WQ_inf, WK_inf,
                                                   Qt, Kt, Qi, Ki);
  k_qks_mfma<<<dim3(R_, H_, 4), 512, 0, stream>>>(Qt, Kt, Qi, Ki, St, Si,
                                                  sMt, sDt, sMi, sDi);
  k_br<<<dim3(R_ + C_, H_), 256, 0, stream>>>(St, Si, sMt, sDt, sMi, sDi,
                                              idx_t, idx_i, bst, bsi, BRt, BRi);

  k_bscs<<<1600, 256, 0, stream>>>(BRt, BRi, Ssq, Tsq, outBS, outCS);
  k_proj_os<<<64, 128, 0, stream>>>(emb, idx_i, cov, W_os, b_os, projb);
  k_os<<<dim3(C_, R_), 256, 0, stream>>>(emb, projb, outOS);

  k_ln_final<<<dim3(R_, 3), 256, 0, stream>>>(outBS, bs_w, bs_b, cs_w, cs_b, os_w, os_b);
}

// Round 4
// 149.022 us; speedup vs baseline: 3.7261x; 1.1010x over previous
//
#include <hip/hip_runtime.h>
#include <math.h>

#define R_ 25
#define N_ 256
#define C_ 64
#define E_ 128
#define H_ 8
#define NC_ 27

typedef _Float16 f16x8 __attribute__((ext_vector_type(8)));
typedef float f32x16 __attribute__((ext_vector_type(16)));

union HU { ushort s; _Float16 h; };
__device__ __forceinline__ ushort ftoh(float f) { HU u; u.h = (_Float16)f; return u.s; }
__device__ __forceinline__ float htof(ushort s) { HU u; u.s = s; return (float)u.h; }

__device__ __forceinline__ float waveReduceSum(float v) {
  #pragma unroll
  for (int off = 32; off > 0; off >>= 1) v += __shfl_xor(v, off);
  return v;
}

// -------------------- 1. emb layernorm -> f16 (4 rows/block) --------------------
__global__ void k_emb_ln16(const float* __restrict__ emb, const float* __restrict__ w,
                           const float* __restrict__ b, ushort* __restrict__ out) {
  int row = blockIdx.x * 4 + (threadIdx.x >> 6);   // 6400 rows
  int lane = threadIdx.x & 63;
  const float2* x = (const float2*)(emb + (size_t)row * E_);
  float2 v = x[lane];
  float s = waveReduceSum(v.x + v.y);
  float m = s * (1.0f / 128.0f);
  float d0 = v.x - m, d1 = v.y - m;
  float ss = waveReduceSum(d0 * d0 + d1 * d1);
  float inv = 1.0f / sqrtf(ss * (1.0f / 128.0f) + 1e-16f);
  float2 wv = ((const float2*)w)[lane];
  float2 bv = ((const float2*)b)[lane];
  uint u = (uint)ftoh(d0 * inv * wv.x + bv.x) | ((uint)ftoh(d1 * inv * wv.y + bv.y) << 16);
  ((uint*)out)[(size_t)row * 64 + lane] = u;
}

// -------------------- 2. mean over trailing 4 (both sets) --------------------
__global__ void k_mean4_all(const float* __restrict__ bus_t, const float* __restrict__ bus_i,
                            float* __restrict__ bst, float* __restrict__ bsi) {
  int i = blockIdx.x * 256 + threadIdx.x;
  if (i < R_ * N_) {
    size_t row = (size_t)(i >> 8) * (C_ * N_) + (i & 255);
    float4 v = *(const float4*)&bus_t[row * 4];
    bst[i] = (v.x + v.y + v.z + v.w) * 0.25f;
  }
  int j = i - R_ * N_;
  if (j >= 0 && j < C_ * N_) {
    float4 v = *(const float4*)&bus_i[(size_t)j * 4];
    bsi[j] = (v.x + v.y + v.z + v.w) * 0.25f;
  }
}

// -------------------- 3. sqrt(softmax(mean4 over 27)) (both sets) ----------
__global__ void k_sqsm_all(const float* __restrict__ cus_t, const float* __restrict__ cus_i,
                           float* __restrict__ Ssq, float* __restrict__ Tsq) {
  int i = blockIdx.x * 256 + threadIdx.x;
  const float* src; float* dst; size_t base; int oi;
  if (i < R_ * N_) {
    src = cus_t; dst = Ssq; oi = i;
    base = ((size_t)(i >> 8) * (C_ * N_) + (i & 255)) * (NC_ * 4);
  } else {
    int j = i - R_ * N_;
    if (j >= C_ * N_) return;
    src = cus_i; dst = Tsq; oi = j;
    base = ((size_t)(j >> 8) * N_ + (j & 255)) * (NC_ * 4);
  }
  float v[NC_];
  float mx = -1e30f;
  #pragma unroll
  for (int j = 0; j < NC_; ++j) {
    float4 t = *(const float4*)&src[base + j * 4];
    v[j] = (t.x + t.y + t.z + t.w) * 0.25f;
    mx = fmaxf(mx, v[j]);
  }
  float se = 0.0f;
  #pragma unroll
  for (int j = 0; j < NC_; ++j) se += expf(v[j] - mx);
  float lse = mx + logf(se);
  #pragma unroll
  for (int j = 0; j < NC_; ++j) dst[(size_t)oi * NC_ + j] = expf(0.5f * (v[j] - lse));
}

// -------------------- 4. group lists: l's sharing the same r --------------------
__global__ void k_groups(const int* __restrict__ idx_t, const int* __restrict__ idx_i,
                         int* __restrict__ cnt, int* __restrict__ lst) {
  int t = threadIdx.x;   // 64
  if (t < 2 * R_) cnt[t] = 0;
  __syncthreads();
  if (t < R_) {
    int rr = idx_t[t * C_];
    int pos = atomicAdd(&cnt[rr], 1);
    lst[rr * 64 + pos] = t;
  }
  if (t < C_) {
    int rr = idx_i[t];
    int pos = atomicAdd(&cnt[R_ + rr], 1);
    lst[(R_ + rr) * 64 + pos] = t;
  }
}

// -------------------- 5. Gt[set,h][e'][e] = sum_f WQ[h,f,e]*WK[h,f,e']/sqrt(E) ---
__global__ __launch_bounds__(512) void k_gt(
    const float* __restrict__ WQt_, const float* __restrict__ WKt_,
    const float* __restrict__ WQi_, const float* __restrict__ WKi_,
    ushort* __restrict__ Gt) {
  int h = blockIdx.x, set = blockIdx.y;
  const float* WQ = (set ? WQi_ : WQt_) + ((size_t)h << 14);
  const float* WK = (set ? WKi_ : WKt_) + ((size_t)h << 14);
  __shared__ float Aq[128 * 133];
  __shared__ float Ak[128 * 133];
  int t = threadIdx.x;
  for (int i = t; i < 16384; i += 512) {
    int f = i >> 7, e = i & 127;
    Aq[e * 133 + f] = WQ[i];
    Ak[e * 133 + f] = WK[i];
  }
  __syncthreads();
  int ep = t & 127, ch = (t >> 7) << 5;
  const float* krow = &Ak[ep * 133];
  const float scale = 0.08838834764831845f;   // 1/sqrt(128)
  ushort* Go = Gt + (((size_t)(set * H_ + h)) << 14);
  for (int j = 0; j < 32; ++j) {
    int e = ch + j;
    const float* qrow = &Aq[e * 133];
    float acc = 0.0f;
    #pragma unroll 8
    for (int f = 0; f < 128; ++f) acc += qrow[f] * krow[f];
    Go[(ep << 7) + e] = ftoh(acc * scale);
  }
}

// -------------------- 6. fused attention: S = ELN*Gt*ELN^T -> softmax -> BR ----
// grid (25, 8, 2). Never materializes S.
__global__ __launch_bounds__(512) void k_attn_fused(
    const ushort* __restrict__ emb16, const ushort* __restrict__ GtAll,
    const int* __restrict__ cnt, const int* __restrict__ lst,
    const float* __restrict__ bst, const float* __restrict__ bsi,
    float* __restrict__ BRt, float* __restrict__ BRi) {
  int r = blockIdx.x, h = blockIdx.y, set = blockIdx.z;
  int g = set * R_ + r;
  int L = cnt[g];
  if (L == 0) return;                       // nobody consumes this (r,set)
  __shared__ ushort ELN[256 * 128];         // 64KB
  __shared__ ushort TA[128 * 128];          // 32KB: Gt staging, then T rows 0..127
  __shared__ ushort TB[128 * 128];          // 32KB: T rows 128..255
  __shared__ float redA[8 * 128];           // 4KB
  __shared__ float redB[8 * 128];           // 4KB
  __shared__ float gM[128], gD[128];
  int t = threadIdx.x;
  // stage ELN_r (swizzled)
  const uint4* Ep = (const uint4*)(emb16 + ((size_t)r << 15));
  for (int c = t; c < 4096; c += 512) {
    int n = c >> 4, s = c & 15;
    uint4 v = Ep[c];
    *(uint4*)&ELN[(n << 7) + ((s << 3) ^ ((n & 15) << 3))] = v;
  }
  // stage Gt (swizzled)
  const uint4* Gp = (const uint4*)(GtAll + ((size_t)(set * H_ + h) << 14));
  for (int c = t; c < 2048; c += 512) {
    int e2 = c >> 4, s = c & 15;
    uint4 v = Gp[c];
    *(uint4*)&TA[(e2 << 7) + ((s << 3) ^ ((e2 & 15) << 3))] = v;
  }
  __syncthreads();
  int w = t >> 6, l = t & 63, lo = l & 31, hi = l >> 5;
  // ---- T = ELN * Gt (T[n,e'] = sum_e ELN[n,e]*Gt[e'][e]) ----
  f32x16 tacc[4];
  #pragma unroll
  for (int i = 0; i < 4; ++i)
    #pragma unroll
    for (int j = 0; j < 16; ++j) tacc[i][j] = 0.0f;
  int n = (w << 5) + lo;
  #pragma unroll
  for (int ks = 0; ks < 8; ++ks) {
    f16x8 a = *(const f16x8*)&ELN[(n << 7) + (((ks << 4) + (hi << 3)) ^ ((n & 15) << 3))];
    #pragma unroll
    for (int tl = 0; tl < 4; ++tl) {
      int f = (tl << 5) + lo;
      f16x8 b = *(const f16x8*)&TA[(f << 7) + (((ks << 4) + (hi << 3)) ^ ((f & 15) << 3))];
      tacc[tl] = __builtin_amdgcn_mfma_f32_32x32x16_f16(a, b, tacc[tl], 0, 0, 0);
    }
  }
  __syncthreads();   // all waves done reading Gt from TA
  // write T (f16, swizzled): rows (w<<5)+..., waves 0-3 -> TA, 4-7 -> TB
  {
    ushort* Tl = (w < 4) ? TA : TB;
    #pragma unroll
    for (int tl = 0; tl < 4; ++tl)
      #pragma unroll
      for (int rg = 0; rg < 16; ++rg) {
        int row = ((w & 3) << 5) + (rg & 3) + ((rg >> 2) << 3) + (hi << 2);
        int col = (tl << 5) + lo;
        Tl[(row << 7) + (col ^ ((row & 15) << 3))] = ftoh(tacc[tl][rg]);
      }
  }
  __syncthreads();
  const float* wv = set ? bsi : bst;
  float* BR = set ? BRi : BRt;
  const ushort* Tl = (w < 4) ? TA : TB;
  int rrow = n & 127;
  int baseRow = (w << 5) + (hi << 2);
  // ---- S = T * ELN^T, softmax over n, BR — per m-half ----
  for (int mh = 0; mh < 2; ++mh) {
    f32x16 acc[4];
    #pragma unroll
    for (int i = 0; i < 4; ++i)
      #pragma unroll
      for (int j = 0; j < 16; ++j) acc[i][j] = 0.0f;
    #pragma unroll
    for (int ks = 0; ks < 8; ++ks) {
      f16x8 a = *(const f16x8*)&Tl[(rrow << 7) + (((ks << 4) + (hi << 3)) ^ ((rrow & 15) << 3))];
      #pragma unroll
      for (int tl = 0; tl < 4; ++tl) {
        int m = (mh << 7) + (tl << 5) + lo;
        f16x8 b = *(const f16x8*)&ELN[(m << 7) + (((ks << 4) + (hi << 3)) ^ ((m & 15) << 3))];
        acc[tl] = __builtin_amdgcn_mfma_f32_32x32x16_f16(a, b, acc[tl], 0, 0, 0);
      }
    }
    // column max over n
    #pragma unroll
    for (int tl = 0; tl < 4; ++tl) {
      float mx = acc[tl][0];
      #pragma unroll
      for (int rg = 1; rg < 16; ++rg) mx = fmaxf(mx, acc[tl][rg]);
      mx = fmaxf(mx, __shfl_xor(mx, 32));
      if (hi == 0) redA[(w << 7) + (tl << 5) + lo] = mx;
    }
    __syncthreads();
    if (t < 128) {
      float gm = redA[t];
      #pragma unroll
      for (int ww = 1; ww < 8; ++ww) gm = fmaxf(gm, redA[(ww << 7) + t]);
      gM[t] = gm;
    }
    __syncthreads();
    // exp in place + column denominator
    #pragma unroll
    for (int tl = 0; tl < 4; ++tl) {
      float gmv = gM[(tl << 5) + lo];
      float s = 0.0f;
      #pragma unroll
      for (int rg = 0; rg < 16; ++rg) {
        acc[tl][rg] = __expf(acc[tl][rg] - gmv);
        s += acc[tl][rg];
      }
      s += __shfl_xor(s, 32);
      if (hi == 0) redB[(w << 7) + (tl << 5) + lo] = s;
    }
    __syncthreads();
    if (t < 128) {
      float d = 0.0f;
      #pragma unroll
      for (int ww = 0; ww < 8; ++ww) d += redB[(ww << 7) + t];
      gD[t] = d;
    }
    __syncthreads();
    // BR for each l in this r's group
    for (int li = 0; li < L; ++li) {
      int ll = lst[g * 64 + li];
      float wreg[16];
      #pragma unroll
      for (int rg = 0; rg < 16; ++rg)
        wreg[rg] = wv[ll * N_ + baseRow + (rg & 3) + ((rg >> 2) << 3)];
      #pragma unroll
      for (int tl = 0; tl < 4; ++tl) {
        float part = 0.0f;
        #pragma unroll
        for (int rg = 0; rg < 16; ++rg) part += wreg[rg] * acc[tl][rg];
        part += __shfl_xor(part, 32);
        if (hi == 0) redA[(w << 7) + (tl << 5) + lo] = part;
      }
      __syncthreads();
      if (t < 128) {
        float s = 0.0f;
        #pragma unroll
        for (int ww = 0; ww < 8; ++ww) s += redA[(ww << 7) + t];
        BR[((size_t)ll * N_ + (mh << 7) + t) * H_ + h] = s / gD[t];
      }
      __syncthreads();
    }
  }
}

// -------------------- 7. BS + CS fused --------------------
__global__ void k_bscs(const float* __restrict__ BRt, const float* __restrict__ BRi,
                       const float* __restrict__ Ssq, const float* __restrict__ Tsq,
                       float* __restrict__ outBS, float* __restrict__ outCS) {
  int i = blockIdx.x * 256 + threadIdx.x;   // < 409600
  int n = i & 255, c = (i >> 8) & 63, l = i >> 14;
  const float4* a = (const float4*)&BRt[((size_t)l * N_ + n) * H_];
  const float4* b = (const float4*)&BRi[((size_t)c * N_ + n) * H_];
  float4 a0 = a[0], a1 = a[1], b0 = b[0], b1 = b[1];
  float dot = a0.x * b0.x + a0.y * b0.y + a0.z * b0.z + a0.w * b0.w
            + a1.x * b1.x + a1.y * b1.y + a1.z * b1.z + a1.w * b1.w;
  float na = a0.x * a0.x + a0.y * a0.y + a0.z * a0.z + a0.w * a0.w
           + a1.x * a1.x + a1.y * a1.y + a1.z * a1.z + a1.w * a1.w;
  float nb = b0.x * b0.x + b0.y * b0.y + b0.z * b0.z + b0.w * b0.w
           + b1.x * b1.x + b1.y * b1.y + b1.z * b1.z + b1.w * b1.w;
  outBS[i] = dot / fmaxf(sqrtf(na) * sqrtf(nb), 1e-15f);

  const float* sp = &Ssq[((size_t)l * N_ + n) * NC_];
  const float* tp = &Tsq[((size_t)c * N_ + n) * NC_];
  float d2 = 0.0f;
  #pragma unroll
  for (int j = 0; j < NC_; ++j) d2 += sp[j] * tp[j];
  outCS[i] = logf(d2) * (1.0f / 27.0f);
}

// -------------------- 8. OS projection --------------------
__global__ void k_proj_os(const float* __restrict__ emb, const int* __restrict__ idxi,
                          const int* __restrict__ biz, const float* __restrict__ Wos,
                          const float* __restrict__ bos, float* __restrict__ proj) {
  int c = blockIdx.x;       // 64
  int f = threadIdx.x;      // 128
  __shared__ float er[E_];
  int row = idxi[c] * N_ + biz[c];
  er[f] = emb[(size_t)row * E_ + f];
  __syncthreads();
  float acc = bos[f];
  const float* wr = &Wos[(size_t)f * E_];
  for (int e = 0; e < E_; e += 4) {
    float4 w4 = *(const float4*)&wr[e];
    acc += er[e] * w4.x + er[e + 1] * w4.y + er[e + 2] * w4.z + er[e + 3] * w4.w;
  }
  proj[c * E_ + f] = acc;
}

// grid (25, 8): block (l, cg) computes OS[l, cg*8..cg*8+8, :]
__global__ void k_os2(const float* __restrict__ emb, const float* __restrict__ proj,
                      float* __restrict__ out) {
  int l = blockIdx.x, cg = blockIdx.y;
  int nIdx = threadIdx.x;                // 256
  __shared__ float pr[8][128];
  for (int i = nIdx; i < 1024; i += 256)
    pr[i >> 7][i & 127] = proj[(cg * 8 + (i >> 7)) * E_ + (i & 127)];
  __syncthreads();
  const float* er = &emb[((size_t)(l * N_) + nIdx) << 7];
  float acc[8] = {0, 0, 0, 0, 0, 0, 0, 0};
  for (int e = 0; e < 128; e += 4) {
    float4 v = *(const float4*)&er[e];
    #pragma unroll
    for (int c = 0; c < 8; ++c)
      acc[c] += v.x * pr[c][e] + v.y * pr[c][e + 1] + v.z * pr[c][e + 2] + v.w * pr[c][e + 3];
  }
  #pragma unroll
  for (int c = 0; c < 8; ++c)
    out[((size_t)l * C_ + cg * 8 + c) * N_ + nIdx] = acc[c];
}

// -------------------- 9. final layernorm over (C,N) per r --------------------
__global__ __launch_bounds__(1024) void k_ln_final(float* __restrict__ out,
    const float* __restrict__ w0, const float* __restrict__ b0,
    const float* __restrict__ w1, const float* __restrict__ b1,
    const float* __restrict__ w2, const float* __restrict__ b2) {
  int r = blockIdx.x, o = blockIdx.y;     // grid (25,3), block 1024
  const float* w = (o == 0) ? w0 : ((o == 1) ? w1 : w2);
  const float* b = (o == 0) ? b0 : ((o == 1) ? b1 : b2);
  float* x = out + (size_t)o * 409600 + (size_t)r * 16384;
  int t = threadIdx.x;
  __shared__ float redm[16];
  float s = 0.0f;
  for (int i = t; i < 16384; i += 1024) s += x[i];
  s = waveReduceSum(s);
  if ((t & 63) == 0) redm[t >> 6] = s;
  __syncthreads();
  float m = 0.0f;
  #pragma unroll
  for (int k = 0; k < 16; ++k) m += redm[k];
  m *= (1.0f / 16384.0f);
  __syncthreads();
  float ss = 0.0f;
  for (int i = t; i < 16384; i += 1024) { float d = x[i] - m; ss += d * d; }
  ss = waveReduceSum(ss);
  if ((t & 63) == 0) redm[t >> 6] = ss;
  __syncthreads();
  float v = 0.0f;
  #pragma unroll
  for (int k = 0; k < 16; ++k) v += redm[k];
  v *= (1.0f / 16384.0f);
  float inv = 1.0f / sqrtf(v + 1e-5f);
  for (int i = t; i < 16384; i += 1024) x[i] = (x[i] - m) * inv * w[i] + b[i];
}

// -------------------- host launcher --------------------
extern "C" void kernel_launch(void* const* d_in, const int* in_sizes, int n_in,
                              void* d_out, int out_size, void* d_ws, size_t ws_size,
                              hipStream_t stream) {
  const float* bus_t  = (const float*)d_in[0];
  const float* bus_i  = (const float*)d_in[1];
  const float* cus_t  = (const float*)d_in[2];
  const float* cus_i  = (const float*)d_in[3];
  const int*   idx_t  = (const int*)d_in[4];
  const int*   idx_i  = (const int*)d_in[5];
  const int*   cov    = (const int*)d_in[6];
  const float* emb    = (const float*)d_in[7];
  const float* ln_w   = (const float*)d_in[8];
  const float* ln_b   = (const float*)d_in[9];
  const float* WQ_trg = (const float*)d_in[10];
  const float* WK_trg = (const float*)d_in[11];
  const float* WQ_inf = (const float*)d_in[12];
  const float* WK_inf = (const float*)d_in[13];
  const float* W_os   = (const float*)d_in[14];
  const float* b_os   = (const float*)d_in[15];
  const float* bs_w   = (const float*)d_in[16];
  const float* bs_b   = (const float*)d_in[17];
  const float* cs_w   = (const float*)d_in[18];
  const float* cs_b   = (const float*)d_in[19];
  const float* os_w   = (const float*)d_in[20];
  const float* os_b   = (const float*)d_in[21];

  float* ws = (float*)d_ws;
  ushort* emb16 = (ushort*)ws;                 // 409600 f32 slots
  float* p = ws + 409600;
  ushort* Gt = (ushort*)p;   p += 131072;      // 16 x 128 x 128 f16
  float* bst = p;            p += 6400;
  float* bsi = p;            p += 16384;
  float* Ssq = p;            p += 172800;
  float* Tsq = p;            p += 442368;
  float* BRt = p;            p += 51200;
  float* BRi = p;            p += 131072;
  float* projb = p;          p += 8192;
  int* cnt = (int*)p;        p += 64;
  int* lst = (int*)p;        p += 3200;

  float* outBS = (float*)d_out;
  float* outCS = outBS + 409600;
  float* outOS = outCS + 409600;

  k_emb_ln16<<<1600, 256, 0, stream>>>(emb, ln_w, ln_b, emb16);
  k_mean4_all<<<89, 256, 0, stream>>>(bus_t, bus_i, bst, bsi);
  k_sqsm_all<<<89, 256, 0, stream>>>(cus_t, cus_i, Ssq, Tsq);
  k_groups<<<1, 64, 0, stream>>>(idx_t, idx_i, cnt, lst);
  k_gt<<<dim3(H_, 2), 512, 0, stream>>>(WQ_trg, WK_trg, WQ_inf, WK_inf, Gt);

  k_attn_fused<<<dim3(R_, H_, 2), 512, 0, stream>>>(emb16, Gt, cnt, lst,
                                                    bst, bsi, BRt, BRi);

  k_bscs<<<1600, 256, 0, stream>>>(BRt, BRi, Ssq, Tsq, outBS, outCS);
  k_proj_os<<<64, 128, 0, stream>>>(emb, idx_i, cov, W_os, b_os, projb);
  k_os2<<<dim3(R_, 8), 256, 0, stream>>>(emb, projb, outOS);

  k_ln_final<<<dim3(R_, 3), 1024, 0, stream>>>(outBS, bs_w, bs_b, cs_w, cs_b, os_w, os_b);
}

// Round 5
// 84.191 us; speedup vs baseline: 6.5953x; 1.7701x over previous
//
#include <hip/hip_runtime.h>
#include <math.h>

#define R_ 25
#define N_ 256
#define C_ 64
#define E_ 128
#define H_ 8
#define NC_ 27
#define SQS 28   // padded row stride for sqrt-softmax tables

typedef _Float16 f16x8 __attribute__((ext_vector_type(8)));
typedef float f32x16 __attribute__((ext_vector_type(16)));

union HU { ushort s; _Float16 h; };
__device__ __forceinline__ ushort ftoh(float f) { HU u; u.h = (_Float16)f; return u.s; }
__device__ __forceinline__ float htof(ushort s) { HU u; u.s = s; return (float)u.h; }

__device__ __forceinline__ float waveReduceSum(float v) {
  #pragma unroll
  for (int off = 32; off > 0; off >>= 1) v += __shfl_xor(v, off);
  return v;
}

// ==================== 1. PREP: emb_ln | mean4 | sqsm | groups | os-proj ====
// grid: [0,1600) emb_ln, [1600,1689) mean4, [1689,1778) sqsm,
//       1778 groups, [1779,1811) os-projection (2 c per block)
__global__ __launch_bounds__(256) void k_prep(
    const float* __restrict__ emb, const float* __restrict__ ln_w,
    const float* __restrict__ ln_b, ushort* __restrict__ emb16,
    const float* __restrict__ bus_t, const float* __restrict__ bus_i,
    float* __restrict__ bst, float* __restrict__ bsi,
    const float* __restrict__ cus_t, const float* __restrict__ cus_i,
    float* __restrict__ Ssq, float* __restrict__ Tsq,
    const int* __restrict__ idx_t, const int* __restrict__ idx_i,
    int* __restrict__ cnt, int* __restrict__ lst,
    const int* __restrict__ biz, const float* __restrict__ Wos,
    const float* __restrict__ bos, float* __restrict__ projb) {
  __shared__ float er2[2][E_];
  int bid = blockIdx.x, t = threadIdx.x;
  if (bid < 1600) {
    // ---- emb layernorm -> f16, 4 rows/block ----
    int row = bid * 4 + (t >> 6);
    int lane = t & 63;
    const float2* x = (const float2*)(emb + (size_t)row * E_);
    float2 v = x[lane];
    float s = waveReduceSum(v.x + v.y);
    float m = s * (1.0f / 128.0f);
    float d0 = v.x - m, d1 = v.y - m;
    float ss = waveReduceSum(d0 * d0 + d1 * d1);
    float inv = 1.0f / sqrtf(ss * (1.0f / 128.0f) + 1e-16f);
    float2 wv = ((const float2*)ln_w)[lane];
    float2 bv = ((const float2*)ln_b)[lane];
    uint u = (uint)ftoh(d0 * inv * wv.x + bv.x) | ((uint)ftoh(d1 * inv * wv.y + bv.y) << 16);
    ((uint*)emb16)[(size_t)row * 64 + lane] = u;
  } else if (bid < 1689) {
    // ---- mean over trailing 4 ----
    int i = (bid - 1600) * 256 + t;
    if (i < R_ * N_) {
      size_t row = (size_t)(i >> 8) * (C_ * N_) + (i & 255);
      float4 v = *(const float4*)&bus_t[row * 4];
      bst[i] = (v.x + v.y + v.z + v.w) * 0.25f;
    }
    int j = i - R_ * N_;
    if (j >= 0 && j < C_ * N_) {
      float4 v = *(const float4*)&bus_i[(size_t)j * 4];
      bsi[j] = (v.x + v.y + v.z + v.w) * 0.25f;
    }
  } else if (bid < 1778) {
    // ---- sqrt(softmax(mean4 over 27)), padded stride 28 ----
    int i = (bid - 1689) * 256 + t;
    const float* src; float* dst; size_t base; int oi;
    if (i < R_ * N_) {
      src = cus_t; dst = Ssq; oi = i;
      base = ((size_t)(i >> 8) * (C_ * N_) + (i & 255)) * (NC_ * 4);
    } else {
      int j = i - R_ * N_;
      if (j >= C_ * N_) return;
      src = cus_i; dst = Tsq; oi = j;
      base = ((size_t)(j >> 8) * N_ + (j & 255)) * (NC_ * 4);
    }
    float v[NC_];
    float mx = -1e30f;
    #pragma unroll
    for (int j = 0; j < NC_; ++j) {
      float4 q = *(const float4*)&src[base + j * 4];
      v[j] = (q.x + q.y + q.z + q.w) * 0.25f;
      mx = fmaxf(mx, v[j]);
    }
    float se = 0.0f;
    #pragma unroll
    for (int j = 0; j < NC_; ++j) se += expf(v[j] - mx);
    float lse = mx + logf(se);
    #pragma unroll
    for (int j = 0; j < NC_; ++j) dst[(size_t)oi * SQS + j] = expf(0.5f * (v[j] - lse));
    dst[(size_t)oi * SQS + NC_] = 0.0f;   // zero pad
  } else if (bid == 1778) {
    // ---- group lists ----
    if (t < 2 * R_) cnt[t] = 0;
    __syncthreads();
    if (t < R_) {
      int rr = idx_t[t * C_];
      int pos = atomicAdd(&cnt[rr], 1);
      lst[rr * 64 + pos] = t;
    }
    if (t < C_) {
      int rr = idx_i[t];
      int pos = atomicAdd(&cnt[R_ + rr], 1);
      lst[(R_ + rr) * 64 + pos] = t;
    }
  } else {
    // ---- OS projection: proj[c][f] = emb[row_c] . Wos[f] + bos[f], 2 c/block ----
    int pb = bid - 1779;            // 0..31
    int ci = t >> 7, f = t & 127;
    int c = pb * 2 + ci;
    int row = idx_i[c] * N_ + biz[c];
    er2[ci][f] = emb[(size_t)row * E_ + f];
    __syncthreads();
    float acc = bos[f];
    const float* wr = &Wos[(size_t)f * E_];
    const float* er = er2[ci];
    for (int e = 0; e < E_; e += 4) {
      float4 w4 = *(const float4*)&wr[e];
      acc += er[e] * w4.x + er[e + 1] * w4.y + er[e + 2] * w4.z + er[e + 3] * w4.w;
    }
    projb[c * E_ + f] = acc;
  }
}

// ==================== 2. Gt via MFMA =======================================
// Gt[set,h][e'][e] = sum_f WK[h,f,e'] * WQ[h,f,e] / sqrt(E)
__global__ __launch_bounds__(512) void k_gt_mfma(
    const float* __restrict__ WQt_, const float* __restrict__ WKt_,
    const float* __restrict__ WQi_, const float* __restrict__ WKi_,
    ushort* __restrict__ Gt) {
  int h = blockIdx.x, set = blockIdx.y;
  const float* WQ = (set ? WQi_ : WQt_) + ((size_t)h << 14);
  const float* WK = (set ? WKi_ : WKt_) + ((size_t)h << 14);
  __shared__ uint QT[128 * 64];   // [e][f2 swz]  (u32 = f16 pair along f)
  __shared__ uint KT[128 * 64];   // [e'][f2 swz]
  int t = threadIdx.x;
  for (int j = t; j < 8192; j += 512) {
    int e = j & 127, f2 = j >> 7;
    int wi = (f2 << 8) + e;               // (2*f2)*128 + e
    float q0 = WQ[wi], q1 = WQ[wi + 128];
    float k0 = WK[wi], k1 = WK[wi + 128];
    int idx = (e << 6) + (f2 ^ ((e & 15) << 2));
    QT[idx] = (uint)ftoh(q0) | ((uint)ftoh(q1) << 16);
    KT[idx] = (uint)ftoh(k0) | ((uint)ftoh(k1) << 16);
  }
  __syncthreads();
  int w = t >> 6, l = t & 63, lo = l & 31, hi = l >> 5;
  int m0 = (w & 3) << 5, n0 = (w >> 2) << 6;
  f32x16 acc[2];
  #pragma unroll
  for (int i = 0; i < 2; ++i)
    #pragma unroll
    for (int j = 0; j < 16; ++j) acc[i][j] = 0.0f;
  int mrow = m0 + lo;
  #pragma unroll
  for (int ks = 0; ks < 8; ++ks) {
    int f2b = (ks << 3) + (hi << 2);
    f16x8 a = *(const f16x8*)&KT[(mrow << 6) + (f2b ^ ((mrow & 15) << 2))];
    #pragma unroll
    for (int tl = 0; tl < 2; ++tl) {
      int ncol = n0 + (tl << 5) + lo;
      f16x8 b = *(const f16x8*)&QT[(ncol << 6) + (f2b ^ ((ncol & 15) << 2))];
      acc[tl] = __builtin_amdgcn_mfma_f32_32x32x16_f16(a, b, acc[tl], 0, 0, 0);
    }
  }
  const float scale = 0.08838834764831845f;   // 1/sqrt(128)
  ushort* Go = Gt + (((size_t)(set * H_ + h)) << 14);
  #pragma unroll
  for (int tl = 0; tl < 2; ++tl)
    #pragma unroll
    for (int rg = 0; rg < 16; ++rg) {
      int row = m0 + (rg & 3) + ((rg >> 2) << 3) + (hi << 2);
      int col = n0 + (tl << 5) + lo;
      Go[(row << 7) + col] = ftoh(acc[tl][rg] * scale);
    }
}

// ==================== 3. fused attention: S = ELN*Gt*ELN^T -> softmax -> BR
__global__ __launch_bounds__(512) void k_attn_fused(
    const ushort* __restrict__ emb16, const ushort* __restrict__ GtAll,
    const int* __restrict__ cnt, const int* __restrict__ lst,
    const float* __restrict__ bst, const float* __restrict__ bsi,
    float* __restrict__ BRt, float* __restrict__ BRi) {
  int r = blockIdx.x, h = blockIdx.y, set = blockIdx.z;
  int g = set * R_ + r;
  int L = cnt[g];
  if (L == 0) return;
  __shared__ ushort ELN[256 * 128];
  __shared__ ushort TA[128 * 128];
  __shared__ ushort TB[128 * 128];
  __shared__ float redA[8 * 128];
  __shared__ float redB[8 * 128];
  __shared__ float gM[128], gD[128];
  int t = threadIdx.x;
  const uint4* Ep = (const uint4*)(emb16 + ((size_t)r << 15));
  for (int c = t; c < 4096; c += 512) {
    int n = c >> 4, s = c & 15;
    uint4 v = Ep[c];
    *(uint4*)&ELN[(n << 7) + ((s << 3) ^ ((n & 15) << 3))] = v;
  }
  const uint4* Gp = (const uint4*)(GtAll + ((size_t)(set * H_ + h) << 14));
  for (int c = t; c < 2048; c += 512) {
    int e2 = c >> 4, s = c & 15;
    uint4 v = Gp[c];
    *(uint4*)&TA[(e2 << 7) + ((s << 3) ^ ((e2 & 15) << 3))] = v;
  }
  __syncthreads();
  int w = t >> 6, l = t & 63, lo = l & 31, hi = l >> 5;
  // ---- T = ELN * Gt ----
  f32x16 tacc[4];
  #pragma unroll
  for (int i = 0; i < 4; ++i)
    #pragma unroll
    for (int j = 0; j < 16; ++j) tacc[i][j] = 0.0f;
  int n = (w << 5) + lo;
  #pragma unroll
  for (int ks = 0; ks < 8; ++ks) {
    f16x8 a = *(const f16x8*)&ELN[(n << 7) + (((ks << 4) + (hi << 3)) ^ ((n & 15) << 3))];
    #pragma unroll
    for (int tl = 0; tl < 4; ++tl) {
      int f = (tl << 5) + lo;
      f16x8 b = *(const f16x8*)&TA[(f << 7) + (((ks << 4) + (hi << 3)) ^ ((f & 15) << 3))];
      tacc[tl] = __builtin_amdgcn_mfma_f32_32x32x16_f16(a, b, tacc[tl], 0, 0, 0);
    }
  }
  __syncthreads();
  {
    ushort* Tl = (w < 4) ? TA : TB;
    #pragma unroll
    for (int tl = 0; tl < 4; ++tl)
      #pragma unroll
      for (int rg = 0; rg < 16; ++rg) {
        int row = ((w & 3) << 5) + (rg & 3) + ((rg >> 2) << 3) + (hi << 2);
        int col = (tl << 5) + lo;
        Tl[(row << 7) + (col ^ ((row & 15) << 3))] = ftoh(tacc[tl][rg]);
      }
  }
  __syncthreads();
  const float* wv = set ? bsi : bst;
  float* BR = set ? BRi : BRt;
  const ushort* Tl = (w < 4) ? TA : TB;
  int rrow = n & 127;
  int baseRow = (w << 5) + (hi << 2);
  for (int mh = 0; mh < 2; ++mh) {
    f32x16 acc[4];
    #pragma unroll
    for (int i = 0; i < 4; ++i)
      #pragma unroll
      for (int j = 0; j < 16; ++j) acc[i][j] = 0.0f;
    #pragma unroll
    for (int ks = 0; ks < 8; ++ks) {
      f16x8 a = *(const f16x8*)&Tl[(rrow << 7) + (((ks << 4) + (hi << 3)) ^ ((rrow & 15) << 3))];
      #pragma unroll
      for (int tl = 0; tl < 4; ++tl) {
        int m = (mh << 7) + (tl << 5) + lo;
        f16x8 b = *(const f16x8*)&ELN[(m << 7) + (((ks << 4) + (hi << 3)) ^ ((m & 15) << 3))];
        acc[tl] = __builtin_amdgcn_mfma_f32_32x32x16_f16(a, b, acc[tl], 0, 0, 0);
      }
    }
    #pragma unroll
    for (int tl = 0; tl < 4; ++tl) {
      float mx = acc[tl][0];
      #pragma unroll
      for (int rg = 1; rg < 16; ++rg) mx = fmaxf(mx, acc[tl][rg]);
      mx = fmaxf(mx, __shfl_xor(mx, 32));
      if (hi == 0) redA[(w << 7) + (tl << 5) + lo] = mx;
    }
    __syncthreads();
    if (t < 128) {
      float gm = redA[t];
      #pragma unroll
      for (int ww = 1; ww < 8; ++ww) gm = fmaxf(gm, redA[(ww << 7) + t]);
      gM[t] = gm;
    }
    __syncthreads();
    #pragma unroll
    for (int tl = 0; tl < 4; ++tl) {
      float gmv = gM[(tl << 5) + lo];
      float s = 0.0f;
      #pragma unroll
      for (int rg = 0; rg < 16; ++rg) {
        acc[tl][rg] = __expf(acc[tl][rg] - gmv);
        s += acc[tl][rg];
      }
      s += __shfl_xor(s, 32);
      if (hi == 0) redB[(w << 7) + (tl << 5) + lo] = s;
    }
    __syncthreads();
    if (t < 128) {
      float d = 0.0f;
      #pragma unroll
      for (int ww = 0; ww < 8; ++ww) d += redB[(ww << 7) + t];
      gD[t] = d;
    }
    __syncthreads();
    for (int li = 0; li < L; ++li) {
      int ll = lst[g * 64 + li];
      float wreg[16];
      #pragma unroll
      for (int rg = 0; rg < 16; ++rg)
        wreg[rg] = wv[ll * N_ + baseRow + (rg & 3) + ((rg >> 2) << 3)];
      #pragma unroll
      for (int tl = 0; tl < 4; ++tl) {
        float part = 0.0f;
        #pragma unroll
        for (int rg = 0; rg < 16; ++rg) part += wreg[rg] * acc[tl][rg];
        part += __shfl_xor(part, 32);
        if (hi == 0) redA[(w << 7) + (tl << 5) + lo] = part;
      }
      __syncthreads();
      if (t < 128) {
        float s = 0.0f;
        #pragma unroll
        for (int ww = 0; ww < 8; ++ww) s += redA[(ww << 7) + t];
        BR[((size_t)ll * N_ + (mh << 7) + t) * H_ + h] = s / gD[t];
      }
      __syncthreads();
    }
  }
}

// ==================== 4. BS + CS + OS ======================================
// grid: [0,1600) bscs, [1600,1800) os-gemm (l = o>>3, cg = o&7)
__global__ __launch_bounds__(256) void k_bscs_os(
    const float* __restrict__ BRt, const float* __restrict__ BRi,
    const float* __restrict__ Ssq, const float* __restrict__ Tsq,
    const float* __restrict__ emb, const float* __restrict__ projb,
    float* __restrict__ outBS, float* __restrict__ outCS,
    float* __restrict__ outOS) {
  __shared__ float pr[8][E_];
  int bid = blockIdx.x, t = threadIdx.x;
  if (bid < 1600) {
    int i = bid * 256 + t;
    int n = i & 255, c = (i >> 8) & 63, l = i >> 14;
    const float4* a = (const float4*)&BRt[((size_t)l * N_ + n) * H_];
    const float4* b = (const float4*)&BRi[((size_t)c * N_ + n) * H_];
    float4 a0 = a[0], a1 = a[1], b0 = b[0], b1 = b[1];
    float dot = a0.x * b0.x + a0.y * b0.y + a0.z * b0.z + a0.w * b0.w
              + a1.x * b1.x + a1.y * b1.y + a1.z * b1.z + a1.w * b1.w;
    float na = a0.x * a0.x + a0.y * a0.y + a0.z * a0.z + a0.w * a0.w
             + a1.x * a1.x + a1.y * a1.y + a1.z * a1.z + a1.w * a1.w;
    float nb = b0.x * b0.x + b0.y * b0.y + b0.z * b0.z + b0.w * b0.w
             + b1.x * b1.x + b1.y * b1.y + b1.z * b1.z + b1.w * b1.w;
    outBS[i] = dot / fmaxf(sqrtf(na) * sqrtf(nb), 1e-15f);

    const float4* sp = (const float4*)&Ssq[((size_t)l * N_ + n) * SQS];
    const float4* tp = (const float4*)&Tsq[((size_t)c * N_ + n) * SQS];
    float d2 = 0.0f;
    #pragma unroll
    for (int j = 0; j < 7; ++j) {
      float4 sv = sp[j], tv = tp[j];
      d2 += sv.x * tv.x + sv.y * tv.y + sv.z * tv.z + sv.w * tv.w;
    }
    outCS[i] = logf(d2) * (1.0f / 27.0f);
  } else {
    int o = bid - 1600;
    int l = o >> 3, cg = o & 7;
    for (int i = t; i < 1024; i += 256)
      pr[i >> 7][i & 127] = projb[(cg * 8 + (i >> 7)) * E_ + (i & 127)];
    __syncthreads();
    const float* er = &emb[((size_t)(l * N_) + t) << 7];
    float acc[8] = {0, 0, 0, 0, 0, 0, 0, 0};
    for (int e = 0; e < 128; e += 4) {
      float4 v = *(const float4*)&er[e];
      #pragma unroll
      for (int c = 0; c < 8; ++c)
        acc[c] += v.x * pr[c][e] + v.y * pr[c][e + 1] + v.z * pr[c][e + 2] + v.w * pr[c][e + 3];
    }
    #pragma unroll
    for (int c = 0; c < 8; ++c)
      outOS[((size_t)l * C_ + cg * 8 + c) * N_ + t] = acc[c];
  }
}

// ==================== 5. final layernorm over (C,N) per r ==================
__global__ __launch_bounds__(1024) void k_ln_final(float* __restrict__ out,
    const float* __restrict__ w0, const float* __restrict__ b0,
    const float* __restrict__ w1, const float* __restrict__ b1,
    const float* __restrict__ w2, const float* __restrict__ b2) {
  int r = blockIdx.x, o = blockIdx.y;     // grid (25,3)
  const float* w = (o == 0) ? w0 : ((o == 1) ? w1 : w2);
  const float* b = (o == 0) ? b0 : ((o == 1) ? b1 : b2);
  float* x = out + (size_t)o * 409600 + (size_t)r * 16384;
  int t = threadIdx.x;
  __shared__ float redm[16];
  float s = 0.0f;
  for (int i = t; i < 16384; i += 1024) s += x[i];
  s = waveReduceSum(s);
  if ((t & 63) == 0) redm[t >> 6] = s;
  __syncthreads();
  float m = 0.0f;
  #pragma unroll
  for (int k = 0; k < 16; ++k) m += redm[k];
  m *= (1.0f / 16384.0f);
  __syncthreads();
  float ss = 0.0f;
  for (int i = t; i < 16384; i += 1024) { float d = x[i] - m; ss += d * d; }
  ss = waveReduceSum(ss);
  if ((t & 63) == 0) redm[t >> 6] = ss;
  __syncthreads();
  float v = 0.0f;
  #pragma unroll
  for (int k = 0; k < 16; ++k) v += redm[k];
  v *= (1.0f / 16384.0f);
  float inv = 1.0f / sqrtf(v + 1e-5f);
  for (int i = t; i < 16384; i += 1024) x[i] = (x[i] - m) * inv * w[i] + b[i];
}

// ==================== host launcher ========================================
extern "C" void kernel_launch(void* const* d_in, const int* in_sizes, int n_in,
                              void* d_out, int out_size, void* d_ws, size_t ws_size,
                              hipStream_t stream) {
  const float* bus_t  = (const float*)d_in[0];
  const float* bus_i  = (const float*)d_in[1];
  const float* cus_t  = (const float*)d_in[2];
  const float* cus_i  = (const float*)d_in[3];
  const int*   idx_t  = (const int*)d_in[4];
  const int*   idx_i  = (const int*)d_in[5];
  const int*   cov    = (const int*)d_in[6];
  const float* emb    = (const float*)d_in[7];
  const float* ln_w   = (const float*)d_in[8];
  const float* ln_b   = (const float*)d_in[9];
  const float* WQ_trg = (const float*)d_in[10];
  const float* WK_trg = (const float*)d_in[11];
  const float* WQ_inf = (const float*)d_in[12];
  const float* WK_inf = (const float*)d_in[13];
  const float* W_os   = (const float*)d_in[14];
  const float* b_os   = (const float*)d_in[15];
  const float* bs_w   = (const float*)d_in[16];
  const float* bs_b   = (const float*)d_in[17];
  const float* cs_w   = (const float*)d_in[18];
  const float* cs_b   = (const float*)d_in[19];
  const float* os_w   = (const float*)d_in[20];
  const float* os_b   = (const float*)d_in[21];

  float* ws = (float*)d_ws;
  ushort* emb16 = (ushort*)ws;                 // 409600 f32 slots
  float* p = ws + 409600;
  ushort* Gt = (ushort*)p;   p += 131072;      // 16 x 128 x 128 f16
  float* bst = p;            p += 6400;
  float* bsi = p;            p += 16384;
  float* Ssq = p;            p += R_ * N_ * SQS;   // 179200
  float* Tsq = p;            p += C_ * N_ * SQS;   // 458752
  float* BRt = p;            p += 51200;
  float* BRi = p;            p += 131072;
  float* projb = p;          p += 8192;
  int* cnt = (int*)p;        p += 64;
  int* lst = (int*)p;        p += 3200;

  float* outBS = (float*)d_out;
  float* outCS = outBS + 409600;
  float* outOS = outCS + 409600;

  k_prep<<<1811, 256, 0, stream>>>(emb, ln_w, ln_b, emb16,
                                   bus_t, bus_i, bst, bsi,
                                   cus_t, cus_i, Ssq, Tsq,
                                   idx_t, idx_i, cnt, lst,
                                   cov, W_os, b_os, projb);
  k_gt_mfma<<<dim3(H_, 2), 512, 0, stream>>>(WQ_trg, WK_trg, WQ_inf, WK_inf, Gt);
  k_attn_fused<<<dim3(R_, H_, 2), 512, 0, stream>>>(emb16, Gt, cnt, lst,
                                                    bst, bsi, BRt, BRi);
  k_bscs_os<<<1800, 256, 0, stream>>>(BRt, BRi, Ssq, Tsq, emb, projb,
                                      outBS, outCS, outOS);
  k_ln_final<<<dim3(R_, 3), 1024, 0, stream>>>(outBS, bs_w, bs_b, cs_w, cs_b, os_w, os_b);
}